// Round 3
// baseline (823.636 us; speedup 1.0000x reference)
//
#include <hip/hip_runtime.h>
#include <hip/hip_bf16.h>
#include <math.h>

#define D_MODEL 512
#define D_FF    2048
#define NE      8
#define T_TOK   8192
#define BM      64
#define FSPLIT  2
#define FH      (D_FF / FSPLIT)   // 1024 f per block
#define NFC     (FH / 64)         // 16 chunks of 64

typedef __attribute__((ext_vector_type(8))) short bf16x8;
typedef __attribute__((ext_vector_type(4))) float f32x4;

static __device__ __forceinline__ unsigned short f2bf(float f){
    union { float f; unsigned u; } v; v.f = f;
    unsigned r = v.u + 0x7FFFu + ((v.u >> 16) & 1u);   // RNE
    return (unsigned short)(r >> 16);
}

// ---------------- f32 -> bf16 conversion (weights) ----------------
__global__ __launch_bounds__(256) void cvt_f32_bf16(const float* __restrict__ src,
                                                    unsigned short* __restrict__ dst,
                                                    int n4){
    int i = blockIdx.x * blockDim.x + threadIdx.x;
    int stride = gridDim.x * blockDim.x;
    for (; i < n4; i += stride){
        float4 v = ((const float4*)src)[i];
        ushort4 o;
        o.x = f2bf(v.x); o.y = f2bf(v.y); o.z = f2bf(v.z); o.w = f2bf(v.w);
        ((ushort4*)dst)[i] = o;
    }
}

// ------------- router (fused with x->bf16): logits -> softmax -> top2 -> scatter -------------
__global__ __launch_bounds__(256) void router_kernel(const float* __restrict__ x,
                                                     const float* __restrict__ Wr,
                                                     unsigned short* __restrict__ x_bf,
                                                     float* __restrict__ pair_prob,
                                                     int* __restrict__ lists,
                                                     int* __restrict__ cnt){
    int gid  = blockIdx.x * blockDim.x + threadIdx.x;
    int t    = gid >> 6;              // one wave per token
    int lane = threadIdx.x & 63;
    if (t >= T_TOK) return;
    const float* xr = x + (size_t)t * D_MODEL;
    float xv[8];
    #pragma unroll
    for (int c = 0; c < 8; ++c) xv[c] = xr[lane + 64*c];
    unsigned short* xb = x_bf + (size_t)t * D_MODEL;
    #pragma unroll
    for (int c = 0; c < 8; ++c) xb[lane + 64*c] = f2bf(xv[c]);
    float lg[NE];
    #pragma unroll
    for (int e = 0; e < NE; ++e){
        const float* wr = Wr + (size_t)e * D_MODEL;
        float s = 0.f;
        #pragma unroll
        for (int c = 0; c < 8; ++c) s = fmaf(xv[c], wr[lane + 64*c], s);
        #pragma unroll
        for (int off = 32; off; off >>= 1) s += __shfl_xor(s, off);
        lg[e] = s;
    }
    if (lane == 0){
        float m = lg[0];
        #pragma unroll
        for (int e = 1; e < NE; ++e) m = fmaxf(m, lg[e]);
        float sum = 0.f;
        #pragma unroll
        for (int e = 0; e < NE; ++e) sum += expf(lg[e] - m);
        int i0 = 0; float v0 = lg[0];
        #pragma unroll
        for (int e = 1; e < NE; ++e) if (lg[e] > v0){ v0 = lg[e]; i0 = e; }
        int i1 = -1; float v1 = -1e30f;
        #pragma unroll
        for (int e = 0; e < NE; ++e) if (e != i0 && lg[e] > v1){ v1 = lg[e]; i1 = e; }
        float inv = 1.f / sum;
        pair_prob[2*t]   = expf(v0 - m) * inv;
        pair_prob[2*t+1] = expf(v1 - m) * inv;
        int pos0 = atomicAdd(&cnt[i0], 1);
        lists[i0 * T_TOK + pos0] = 2*t;
        int pos1 = atomicAdd(&cnt[i1], 1);
        lists[i1 * T_TOK + pos1] = 2*t + 1;
    }
}

// ---------------- fused expert FFN ----------------
// 1024 thr (16 waves). tile = 64 pairs of one expert, f-range = 1024 per block.
// GEMM1: wave (tq,fq) -> 16tok x 16f  (4 acc regs)
// GEMM2: wave (th,dq) -> 32tok x 64d  (32 acc regs)
// regs ~105 < hard 128 cap (16-wave block => 4 waves/EU => 1 block/CU, 50% occ)
__global__ __launch_bounds__(1024, 4) void moe_ffn_kernel(const unsigned short* __restrict__ x_bf,
                                                          const unsigned short* __restrict__ W1bf,
                                                          const unsigned short* __restrict__ W2bf,
                                                          const float* __restrict__ pair_prob,
                                                          const int* __restrict__ lists,
                                                          const int* __restrict__ cnt,
                                                          float* __restrict__ out0,
                                                          float* __restrict__ out1){
    __shared__ __align__(16) unsigned char lds_x[BM * 1024];      // 64 rows x 512 bf16, swizzled
    __shared__ __align__(16) unsigned char lds_h[2][BM * 128];    // dbuf: 64 rows x 64 bf16, swizzled

    // XCD-grouped decode: xcd (bid&7) owns experts {eA, eA+4} at f-half sA
    int bid  = blockIdx.x;
    int xcd  = bid & 7, slot = bid >> 3;
    int eA   = xcd >> 1, sA = xcd & 1;
    int eB   = eA + 4;
    int tA   = (cnt[eA] + BM - 1) >> 6;
    int tB   = (cnt[eB] + BM - 1) >> 6;
    int e, sp, tile;
    if (slot < tA)           { e = eA; sp = sA; tile = slot; }
    else if (slot < tA + tB) { e = eB; sp = sA; tile = slot - tA; }
    else return;
    int ne = cnt[e];

    int tid = threadIdx.x;
    // ---- stage gathered X rows (bf16) into swizzled LDS: 64 rows, 16 thr/row, 64B/thr
    {
        int row = tid >> 4;
        int idx = tile * BM + row;
        int tok = 0;
        if (idx < ne) tok = lists[e * T_TOK + idx] >> 1;
        int seg = (tid & 15) * 32;
        const unsigned short* src = x_bf + (size_t)tok * D_MODEL + seg;
        int sw = (row & 7) << 4;
        #pragma unroll
        for (int g = 0; g < 4; ++g){
            int4 v = *(const int4*)(src + g * 8);
            int col2 = (seg + g * 8) * 2;
            *(int4*)(lds_x + row * 1024 + (col2 ^ sw)) = v;
        }
    }
    __syncthreads();

    int wv = tid >> 6, lane = tid & 63, l15 = lane & 15, lk = lane >> 4;
    // GEMM1 roles
    int tq = wv & 3, fq = wv >> 2;         // 16-tok quarter, 16-f quarter
    // GEMM2 roles
    int th = wv & 1, dq = wv >> 1;         // 32-tok half, 64-d eighth
    int swz = (l15 & 7) << 4;
    int g1ar = tq * 16 + l15;              // GEMM1 A row
    int ar0  = th * 32 + l15, ar1 = ar0 + 16;  // GEMM2 A rows

    f32x4 zero4 = {0.f, 0.f, 0.f, 0.f};
    f32x4 yacc[2][4];
    #pragma unroll
    for (int i = 0; i < 2; ++i)
        #pragma unroll
        for (int j = 0; j < 4; ++j) yacc[i][j] = zero4;

    const unsigned short* w1p0 = W1bf + ((size_t)e * D_FF + sp * FH + fq * 16 + l15) * D_MODEL + lk * 8;
    const unsigned short* w2p0 = W2bf + ((size_t)e * D_MODEL + dq * 64 + l15) * D_FF + sp * FH + lk * 8;

    for (int fc = 0; fc < NFC; ++fc){
        // ---- GEMM1: this wave computes 16 tok x 16 f, K = 512
        f32x4 hacc = zero4;
        const unsigned short* w1p = w1p0 + (size_t)(fc * 64) * D_MODEL;
        #pragma unroll
        for (int ks = 0; ks < 16; ++ks){
            int col2 = (ks * 32 + lk * 8) * 2;
            bf16x8 a  = *(const bf16x8*)(lds_x + g1ar * 1024 + (col2 ^ swz));
            bf16x8 bb = *(const bf16x8*)(w1p + ks * 32);
            hacc = __builtin_amdgcn_mfma_f32_16x16x32_bf16(a, bb, hacc, 0, 0, 0);
        }
        // ---- GELU (exact erf) -> bf16 h[cur]
        unsigned char* hb = lds_h[fc & 1];
        {
            int fl2 = (fq * 16 + l15) * 2;
            #pragma unroll
            for (int r = 0; r < 4; ++r){
                int trow = tq * 16 + lk * 4 + r;
                float g = hacc[r];
                g = 0.5f * g * (1.f + erff(g * 0.70710678118654752f));
                *(unsigned short*)(hb + trow * 128 + (fl2 ^ ((trow & 7) << 4))) = f2bf(g);
            }
        }
        // barrier WITHOUT vmcnt drain: global W loads stay in flight
        asm volatile("s_waitcnt lgkmcnt(0)\n\ts_barrier" ::: "memory");
        // ---- GEMM2: this wave 32 tok x 64 d, K=64 chunk
        const unsigned short* w2p = w2p0 + fc * 64;
        #pragma unroll
        for (int ks2 = 0; ks2 < 2; ++ks2){
            int col2 = (ks2 * 32 + lk * 8) * 2;
            bf16x8 a0 = *(const bf16x8*)(hb + ar0 * 128 + (col2 ^ swz));
            bf16x8 a1 = *(const bf16x8*)(hb + ar1 * 128 + (col2 ^ swz));
            #pragma unroll
            for (int nt = 0; nt < 4; ++nt){
                bf16x8 bb = *(const bf16x8*)(w2p + (size_t)nt * 16 * D_FF + ks2 * 32);
                yacc[0][nt] = __builtin_amdgcn_mfma_f32_16x16x32_bf16(a0, bb, yacc[0][nt], 0, 0, 0);
                yacc[1][nt] = __builtin_amdgcn_mfma_f32_16x16x32_bf16(a1, bb, yacc[1][nt], 0, 0, 0);
            }
        }
    }

    // ---- epilogue: dst[tok] += p * Y  (exactly 2 commutative atomics per element per dst)
    float* dst = (sp == 0) ? out0 : out1;
    const int* lrow = lists + e * T_TOK + tile * BM;
    #pragma unroll
    for (int mt = 0; mt < 2; ++mt){
        #pragma unroll
        for (int r = 0; r < 4; ++r){
            int trow = th * 32 + mt * 16 + lk * 4 + r;
            int idx  = tile * BM + trow;
            if (idx < ne){
                int pair = lrow[trow];
                float p  = pair_prob[pair];
                float* orow = dst + (size_t)(pair >> 1) * D_MODEL;
                #pragma unroll
                for (int nt = 0; nt < 4; ++nt){
                    int d = dq * 64 + nt * 16 + l15;
                    atomicAdd(orow + d, p * yacc[mt][nt][r]);
                }
            }
        }
    }
}

// ---------------- fixed-order reduce of the split-1 partial ----------------
__global__ __launch_bounds__(256) void add_partial(float* __restrict__ out,
                                                   const float* __restrict__ part,
                                                   int n4){
    int i = blockIdx.x * blockDim.x + threadIdx.x;
    int stride = gridDim.x * blockDim.x;
    for (; i < n4; i += stride){
        float4 a = ((const float4*)out)[i];
        float4 b = ((const float4*)part)[i];
        a.x += b.x; a.y += b.y; a.z += b.z; a.w += b.w;
        ((float4*)out)[i] = a;
    }
}

extern "C" void kernel_launch(void* const* d_in, const int* in_sizes, int n_in,
                              void* d_out, int out_size, void* d_ws, size_t ws_size,
                              hipStream_t stream){
    const float* x  = (const float*)d_in[0];
    const float* Wr = (const float*)d_in[1];
    const float* W1 = (const float*)d_in[2];
    const float* W2 = (const float*)d_in[3];
    float* out = (float*)d_out;

    char* ws = (char*)d_ws;
    unsigned short* x_bf  = (unsigned short*)(ws);                 //  8,388,608 B
    unsigned short* W1bf  = (unsigned short*)(ws + 8388608);       // 16,777,216 B
    unsigned short* W2bf  = (unsigned short*)(ws + 25165824);      // 16,777,216 B
    float* pair_prob      = (float*)(ws + 41943040);               //     65,536 B
    int*   lists          = (int*)(ws + 42008576);                 //    262,144 B
    int*   cnt            = (int*)(ws + 42270720);                 //         32 B
    const size_t OFF_PART = 42271744;                              // 1KB-aligned
    const size_t NEED     = OFF_PART + (size_t)T_TOK * D_MODEL * 4;
    bool use_partial = ws_size >= NEED;
    float* partial = use_partial ? (float*)(ws + OFF_PART) : out;

    hipMemsetAsync(cnt, 0, NE * sizeof(int), stream);
    hipMemsetAsync(d_out, 0, (size_t)out_size * sizeof(float), stream);
    if (use_partial)
        hipMemsetAsync(partial, 0, (size_t)T_TOK * D_MODEL * 4, stream);

    cvt_f32_bf16<<<2048, 256, 0, stream>>>(W1, W1bf, (NE * D_FF * D_MODEL) / 4);
    cvt_f32_bf16<<<2048, 256, 0, stream>>>(W2, W2bf, (NE * D_MODEL * D_FF) / 4);

    router_kernel<<<(T_TOK * 64) / 256, 256, 0, stream>>>(x, Wr, x_bf, pair_prob, lists, cnt);

    // grid covers worst-case per-xcd tile counts; inactive blocks exit early
    moe_ffn_kernel<<<2080, 1024, 0, stream>>>(x_bf, W1bf, W2bf, pair_prob, lists, cnt, out, partial);

    if (use_partial)
        add_partial<<<2048, 256, 0, stream>>>(out, partial, (T_TOK * D_MODEL) / 4);
}

// Round 4
// 517.290 us; speedup vs baseline: 1.5922x; 1.5922x over previous
//
#include <hip/hip_runtime.h>
#include <hip/hip_bf16.h>
#include <math.h>

#define D_MODEL 512
#define D_FF    2048
#define NE      8
#define T_TOK   8192
#define BM      64
#define FSPLIT  2
#define FH      (D_FF / FSPLIT)   // 1024 f per block
#define FCH     128               // f per chunk
#define NFC     (FH / FCH)        // 8 chunks

typedef __attribute__((ext_vector_type(8))) short bf16x8;
typedef __attribute__((ext_vector_type(4))) float f32x4;

static __device__ __forceinline__ unsigned short f2bf(float f){
    union { float f; unsigned u; } v; v.f = f;
    unsigned r = v.u + 0x7FFFu + ((v.u >> 16) & 1u);   // RNE
    return (unsigned short)(r >> 16);
}
static __device__ __forceinline__ float bf2f(unsigned short u){
    union { unsigned u; float f; } v; v.u = ((unsigned)u) << 16; return v.f;
}

// ---------------- f32 -> bf16 conversion (weights) ----------------
__global__ __launch_bounds__(256) void cvt_f32_bf16(const float* __restrict__ src,
                                                    unsigned short* __restrict__ dst,
                                                    int n4){
    int i = blockIdx.x * blockDim.x + threadIdx.x;
    int stride = gridDim.x * blockDim.x;
    for (; i < n4; i += stride){
        float4 v = ((const float4*)src)[i];
        ushort4 o;
        o.x = f2bf(v.x); o.y = f2bf(v.y); o.z = f2bf(v.z); o.w = f2bf(v.w);
        ((ushort4*)dst)[i] = o;
    }
}

// ------------- router (fused with x->bf16): logits -> softmax -> top2 -> scatter -------------
__global__ __launch_bounds__(256) void router_kernel(const float* __restrict__ x,
                                                     const float* __restrict__ Wr,
                                                     unsigned short* __restrict__ x_bf,
                                                     float* __restrict__ pair_prob,
                                                     int* __restrict__ lists,
                                                     int* __restrict__ cnt){
    int gid  = blockIdx.x * blockDim.x + threadIdx.x;
    int t    = gid >> 6;              // one wave per token
    int lane = threadIdx.x & 63;
    if (t >= T_TOK) return;
    const float* xr = x + (size_t)t * D_MODEL;
    float xv[8];
    #pragma unroll
    for (int c = 0; c < 8; ++c) xv[c] = xr[lane + 64*c];
    unsigned short* xb = x_bf + (size_t)t * D_MODEL;
    #pragma unroll
    for (int c = 0; c < 8; ++c) xb[lane + 64*c] = f2bf(xv[c]);
    float lg[NE];
    #pragma unroll
    for (int e = 0; e < NE; ++e){
        const float* wr = Wr + (size_t)e * D_MODEL;
        float s = 0.f;
        #pragma unroll
        for (int c = 0; c < 8; ++c) s = fmaf(xv[c], wr[lane + 64*c], s);
        #pragma unroll
        for (int off = 32; off; off >>= 1) s += __shfl_xor(s, off);
        lg[e] = s;
    }
    if (lane == 0){
        float m = lg[0];
        #pragma unroll
        for (int e = 1; e < NE; ++e) m = fmaxf(m, lg[e]);
        float sum = 0.f;
        #pragma unroll
        for (int e = 0; e < NE; ++e) sum += expf(lg[e] - m);
        int i0 = 0; float v0 = lg[0];
        #pragma unroll
        for (int e = 1; e < NE; ++e) if (lg[e] > v0){ v0 = lg[e]; i0 = e; }
        int i1 = -1; float v1 = -1e30f;
        #pragma unroll
        for (int e = 0; e < NE; ++e) if (e != i0 && lg[e] > v1){ v1 = lg[e]; i1 = e; }
        float inv = 1.f / sum;
        pair_prob[2*t]   = expf(v0 - m) * inv;
        pair_prob[2*t+1] = expf(v1 - m) * inv;
        int pos0 = atomicAdd(&cnt[i0], 1);
        lists[i0 * T_TOK + pos0] = 2*t;
        int pos1 = atomicAdd(&cnt[i1], 1);
        lists[i1 * T_TOK + pos1] = 2*t + 1;
    }
}

// ---------------- fused expert FFN ----------------
// 512 thr (8 waves), launch_bounds(512,2): VGPR cap 256, LDS 80KB -> 2 blocks/CU.
// tile = 64 pairs of one expert, f-range = FH per block, f-chunk = 128.
// GEMM1: wave wv owns f-slab of 16 (no W1 duplication): 64tok x 16f, hacc[4]
// GEMM2: wave wv owns d-slab of 64 (no W2 duplication): 64tok x 64d, yacc[4][4]
template<int YBUF>
__global__ __launch_bounds__(512, 2) void moe_ffn_kernel(const unsigned short* __restrict__ x_bf,
                                                         const unsigned short* __restrict__ W1bf,
                                                         const unsigned short* __restrict__ W2bf,
                                                         const float* __restrict__ pair_prob,
                                                         const int* __restrict__ lists,
                                                         const int* __restrict__ cnt,
                                                         unsigned short* __restrict__ ybuf,
                                                         float* __restrict__ out0,
                                                         float* __restrict__ out1){
    __shared__ __align__(16) unsigned char lds_x[BM * 1024];   // 64 rows x 512 bf16, swizzled (64KB)
    __shared__ __align__(16) unsigned char lds_h[BM * 256];    // 64 rows x 128 bf16, swizzled (16KB)

    // XCD-grouped decode: xcd (bid&7) owns experts {eA, eA+4} at f-half sA
    int bid  = blockIdx.x;
    int xcd  = bid & 7, slot = bid >> 3;
    int eA   = xcd >> 1, sA = xcd & 1;
    int eB   = eA + 4;
    int tA   = (cnt[eA] + BM - 1) >> 6;
    int tB   = (cnt[eB] + BM - 1) >> 6;
    int e, sp, tile;
    if (slot < tA)           { e = eA; sp = sA; tile = slot; }
    else if (slot < tA + tB) { e = eB; sp = sA; tile = slot - tA; }
    else return;
    int ne = cnt[e];

    int tid = threadIdx.x;
    // ---- stage gathered X rows (bf16) into swizzled LDS: 64 rows, 8 thr/row, 128B/thr
    {
        int row = tid >> 3;
        int idx = tile * BM + row;
        int tok = 0;
        if (idx < ne) tok = lists[e * T_TOK + idx] >> 1;
        int seg = (tid & 7) * 64;
        const unsigned short* src = x_bf + (size_t)tok * D_MODEL + seg;
        int sw = (row & 7) << 4;
        #pragma unroll
        for (int g = 0; g < 8; ++g){
            int4 v = *(const int4*)(src + g * 8);
            int col2 = (seg + g * 8) * 2;
            *(int4*)(lds_x + row * 1024 + (col2 ^ sw)) = v;
        }
    }
    __syncthreads();

    int wv = tid >> 6, lane = tid & 63, l15 = lane & 15, lk = lane >> 4;
    int swz = (l15 & 7) << 4;

    f32x4 zero4 = {0.f, 0.f, 0.f, 0.f};
    f32x4 yacc[4][4];
    #pragma unroll
    for (int i = 0; i < 4; ++i)
        #pragma unroll
        for (int j = 0; j < 4; ++j) yacc[i][j] = zero4;

    // GEMM1: B rows = W1[f = sp*FH + fc*128 + wv*16 + l15], k = d_model
    const unsigned short* w1p0 = W1bf + ((size_t)e * D_FF + sp * FH + wv * 16 + l15) * D_MODEL + lk * 8;
    // GEMM2: B rows = W2[d = wv*64 + nt*16 + l15], k = f
    const unsigned short* w2p0 = W2bf + ((size_t)e * D_MODEL + wv * 64 + l15) * D_FF + sp * FH + lk * 8;

    for (int fc = 0; fc < NFC; ++fc){
        // ---- GEMM1: this wave computes 64 tok x 16 f, K = 512 (4 indep MFMA chains)
        f32x4 hacc[4];
        #pragma unroll
        for (int at = 0; at < 4; ++at) hacc[at] = zero4;
        const unsigned short* w1p = w1p0 + (size_t)(fc * FCH) * D_MODEL;
        #pragma unroll
        for (int ks = 0; ks < 16; ++ks){
            bf16x8 bb = *(const bf16x8*)(w1p + ks * 32);
            int col2 = (ks * 32 + lk * 8) * 2;
            #pragma unroll
            for (int at = 0; at < 4; ++at){
                bf16x8 a = *(const bf16x8*)(lds_x + (at * 16 + l15) * 1024 + (col2 ^ swz));
                hacc[at] = __builtin_amdgcn_mfma_f32_16x16x32_bf16(a, bb, hacc[at], 0, 0, 0);
            }
        }
        // ---- GELU (exact erf) -> bf16 h: this wave writes f-col slab [wv*16+l15] for 64 toks
        {
            int fl2 = (wv * 16 + l15) * 2;
            #pragma unroll
            for (int at = 0; at < 4; ++at){
                #pragma unroll
                for (int r = 0; r < 4; ++r){
                    int tok = at * 16 + lk * 4 + r;
                    float g = hacc[at][r];
                    g = 0.5f * g * (1.f + erff(g * 0.70710678118654752f));
                    *(unsigned short*)(lds_h + tok * 256 + (fl2 ^ ((tok & 7) << 4))) = f2bf(g);
                }
            }
        }
        // barrier WITHOUT vmcnt drain: global W loads stay in flight
        asm volatile("s_waitcnt lgkmcnt(0)\n\ts_barrier" ::: "memory");
        // ---- GEMM2: this wave 64 tok x 64 d, K = 128 chunk
        const unsigned short* w2p = w2p0 + fc * FCH;
        #pragma unroll
        for (int ks2 = 0; ks2 < 4; ++ks2){
            int col2 = (ks2 * 32 + lk * 8) * 2;
            bf16x8 am[4];
            #pragma unroll
            for (int mt = 0; mt < 4; ++mt)
                am[mt] = *(const bf16x8*)(lds_h + (mt * 16 + l15) * 256 + (col2 ^ swz));
            #pragma unroll
            for (int nt = 0; nt < 4; ++nt){
                bf16x8 bb = *(const bf16x8*)(w2p + (size_t)nt * 16 * D_FF + ks2 * 32);
                #pragma unroll
                for (int mt = 0; mt < 4; ++mt)
                    yacc[mt][nt] = __builtin_amdgcn_mfma_f32_16x16x32_bf16(am[mt], bb, yacc[mt][nt], 0, 0, 0);
            }
        }
        // h reads done before next chunk's GELU writes
        asm volatile("s_waitcnt lgkmcnt(0)\n\ts_barrier" ::: "memory");
    }

    // ---- epilogue
    const int* lrow = lists + e * T_TOK + tile * BM;
    if (YBUF){
        // non-atomic: store raw Y (bf16) to ybuf[sp][pair][d]
        #pragma unroll
        for (int mt = 0; mt < 4; ++mt){
            #pragma unroll
            for (int r = 0; r < 4; ++r){
                int trow = mt * 16 + lk * 4 + r;
                int idx  = tile * BM + trow;
                if (idx < ne){
                    int pair = lrow[trow];
                    unsigned short* yrow = ybuf + ((size_t)sp * (2 * T_TOK) + pair) * D_MODEL + wv * 64 + l15;
                    #pragma unroll
                    for (int nt = 0; nt < 4; ++nt)
                        yrow[nt * 16] = f2bf(yacc[mt][nt][r]);
                }
            }
        }
    } else {
        // fallback: weighted atomics (2 commutative adds per element per dst)
        float* dst = (sp == 0) ? out0 : out1;
        #pragma unroll
        for (int mt = 0; mt < 4; ++mt){
            #pragma unroll
            for (int r = 0; r < 4; ++r){
                int trow = mt * 16 + lk * 4 + r;
                int idx  = tile * BM + trow;
                if (idx < ne){
                    int pair = lrow[trow];
                    float p  = pair_prob[pair];
                    float* orow = dst + (size_t)(pair >> 1) * D_MODEL;
                    #pragma unroll
                    for (int nt = 0; nt < 4; ++nt)
                        atomicAdd(orow + wv * 64 + nt * 16 + l15, p * yacc[mt][nt][r]);
                }
            }
        }
    }
}

// ---------------- combine: out[t] = p0*(Y[0][2t]+Y[1][2t]) + p1*(Y[0][2t+1]+Y[1][2t+1]) ----------------
__global__ __launch_bounds__(256) void combine_kernel(const unsigned short* __restrict__ ybuf,
                                                      const float* __restrict__ pair_prob,
                                                      float* __restrict__ out){
    int wave = (blockIdx.x * 256 + threadIdx.x) >> 6;
    int lane = threadIdx.x & 63;
    if (wave >= T_TOK) return;
    int t = wave;
    float p0 = pair_prob[2*t], p1 = pair_prob[2*t+1];
    const unsigned short* ya0 = ybuf + (size_t)(2*t)     * D_MODEL + lane * 8;
    const unsigned short* ya1 = ybuf + (size_t)(2*t + 1) * D_MODEL + lane * 8;
    const unsigned short* yb0 = ya0 + (size_t)(2 * T_TOK) * D_MODEL;
    const unsigned short* yb1 = ya1 + (size_t)(2 * T_TOK) * D_MODEL;
    ushort4 a0[2], a1[2], b0[2], b1[2];
    *(int4*)a0 = *(const int4*)ya0;  *(int4*)a1 = *(const int4*)ya1;
    *(int4*)b0 = *(const int4*)yb0;  *(int4*)b1 = *(const int4*)yb1;
    const unsigned short* pa0 = (const unsigned short*)a0;
    const unsigned short* pa1 = (const unsigned short*)a1;
    const unsigned short* pb0 = (const unsigned short*)b0;
    const unsigned short* pb1 = (const unsigned short*)b1;
    float res[8];
    #pragma unroll
    for (int j = 0; j < 8; ++j)
        res[j] = p0 * (bf2f(pa0[j]) + bf2f(pb0[j])) + p1 * (bf2f(pa1[j]) + bf2f(pb1[j]));
    float* orow = out + (size_t)t * D_MODEL + lane * 8;
    *(float4*)(orow)     = *(float4*)(res);
    *(float4*)(orow + 4) = *(float4*)(res + 4);
}

// ---------------- fixed-order reduce of the split-1 partial (fallback path) ----------------
__global__ __launch_bounds__(256) void add_partial(float* __restrict__ out,
                                                   const float* __restrict__ part,
                                                   int n4){
    int i = blockIdx.x * blockDim.x + threadIdx.x;
    int stride = gridDim.x * blockDim.x;
    for (; i < n4; i += stride){
        float4 a = ((const float4*)out)[i];
        float4 b = ((const float4*)part)[i];
        a.x += b.x; a.y += b.y; a.z += b.z; a.w += b.w;
        ((float4*)out)[i] = a;
    }
}

extern "C" void kernel_launch(void* const* d_in, const int* in_sizes, int n_in,
                              void* d_out, int out_size, void* d_ws, size_t ws_size,
                              hipStream_t stream){
    const float* x  = (const float*)d_in[0];
    const float* Wr = (const float*)d_in[1];
    const float* W1 = (const float*)d_in[2];
    const float* W2 = (const float*)d_in[3];
    float* out = (float*)d_out;

    char* ws = (char*)d_ws;
    unsigned short* x_bf  = (unsigned short*)(ws);                 //  8,388,608 B
    unsigned short* W1bf  = (unsigned short*)(ws + 8388608);       // 16,777,216 B
    unsigned short* W2bf  = (unsigned short*)(ws + 25165824);      // 16,777,216 B
    float* pair_prob      = (float*)(ws + 41943040);               //     65,536 B
    int*   lists          = (int*)(ws + 42008576);                 //    262,144 B
    int*   cnt            = (int*)(ws + 42270720);                 //         32 B
    const size_t OFF_Y    = 42271744;                              // 1KB-aligned
    const size_t Y_BYTES  = (size_t)2 * (2 * T_TOK) * D_MODEL * 2; // 33,554,432 B (bf16)
    bool use_ybuf = ws_size >= OFF_Y + Y_BYTES;
    unsigned short* ybuf = (unsigned short*)(ws + OFF_Y);
    bool use_partial = !use_ybuf && (ws_size >= OFF_Y + (size_t)T_TOK * D_MODEL * 4);
    float* partial = use_partial ? (float*)(ws + OFF_Y) : out;

    hipMemsetAsync(cnt, 0, NE * sizeof(int), stream);
    if (!use_ybuf){
        hipMemsetAsync(d_out, 0, (size_t)out_size * sizeof(float), stream);
        if (use_partial)
            hipMemsetAsync(partial, 0, (size_t)T_TOK * D_MODEL * 4, stream);
    }

    cvt_f32_bf16<<<2048, 256, 0, stream>>>(W1, W1bf, (NE * D_FF * D_MODEL) / 4);
    cvt_f32_bf16<<<2048, 256, 0, stream>>>(W2, W2bf, (NE * D_MODEL * D_FF) / 4);

    router_kernel<<<(T_TOK * 64) / 256, 256, 0, stream>>>(x, Wr, x_bf, pair_prob, lists, cnt);

    // grid covers worst-case per-xcd tile counts; inactive blocks exit early
    if (use_ybuf){
        moe_ffn_kernel<1><<<2080, 512, 0, stream>>>(x_bf, W1bf, W2bf, pair_prob, lists, cnt,
                                                    ybuf, out, out);
        combine_kernel<<<T_TOK / 4, 256, 0, stream>>>(ybuf, pair_prob, out);
    } else {
        moe_ffn_kernel<0><<<2080, 512, 0, stream>>>(x_bf, W1bf, W2bf, pair_prob, lists, cnt,
                                                    ybuf, out, partial);
        if (use_partial)
            add_partial<<<2048, 256, 0, stream>>>(out, partial, (T_TOK * D_MODEL) / 4);
    }
}

// Round 5
// 405.689 us; speedup vs baseline: 2.0302x; 1.2751x over previous
//
#include <hip/hip_runtime.h>
#include <hip/hip_bf16.h>
#include <math.h>

#define D_MODEL 512
#define D_FF    2048
#define NE      8
#define T_TOK   8192
#define NPAIR   (2 * T_TOK)

typedef __attribute__((ext_vector_type(8))) short bf16x8;
typedef __attribute__((ext_vector_type(4))) float f32x4;

static __device__ __forceinline__ unsigned short f2bf(float f){
    union { float f; unsigned u; } v; v.f = f;
    unsigned r = v.u + 0x7FFFu + ((v.u >> 16) & 1u);   // RNE
    return (unsigned short)(r >> 16);
}

// tanh-form GELU via exp2 (abs err <= ~3e-4, well under bf16 rounding of h)
static __device__ __forceinline__ float gelu_f(float x){
    float z = 0.7978845608028654f * (x + 0.044715f * x * x * x);
    float e = __builtin_amdgcn_exp2f(z * 2.8853900817779268f);  // e^(2z)
    float t = 1.f - 2.f * __builtin_amdgcn_rcpf(e + 1.f);       // tanh(z)
    return 0.5f * x * (1.f + t);
}

static __device__ __forceinline__ void gload16(const void* g, void* l){
    __builtin_amdgcn_global_load_lds((const __attribute__((address_space(1))) unsigned int*)g,
                                     (__attribute__((address_space(3))) unsigned int*)l, 16, 0, 0);
}

// ---------------- f32 -> bf16 conversion (weights) ----------------
__global__ __launch_bounds__(256) void cvt_f32_bf16(const float* __restrict__ src,
                                                    unsigned short* __restrict__ dst,
                                                    int n4){
    int i = blockIdx.x * blockDim.x + threadIdx.x;
    int stride = gridDim.x * blockDim.x;
    for (; i < n4; i += stride){
        float4 v = ((const float4*)src)[i];
        ushort4 o;
        o.x = f2bf(v.x); o.y = f2bf(v.y); o.z = f2bf(v.z); o.w = f2bf(v.w);
        ((ushort4*)dst)[i] = o;
    }
}

// ------------- router (fused with x->bf16): logits -> softmax -> top2 -> scatter -------------
__global__ __launch_bounds__(256) void router_kernel(const float* __restrict__ x,
                                                     const float* __restrict__ Wr,
                                                     unsigned short* __restrict__ x_bf,
                                                     float* __restrict__ pair_prob,
                                                     int* __restrict__ lists,
                                                     int* __restrict__ cnt){
    int gid  = blockIdx.x * blockDim.x + threadIdx.x;
    int t    = gid >> 6;
    int lane = threadIdx.x & 63;
    if (t >= T_TOK) return;
    const float* xr = x + (size_t)t * D_MODEL;
    float xv[8];
    #pragma unroll
    for (int c = 0; c < 8; ++c) xv[c] = xr[lane + 64*c];
    unsigned short* xb = x_bf + (size_t)t * D_MODEL;
    #pragma unroll
    for (int c = 0; c < 8; ++c) xb[lane + 64*c] = f2bf(xv[c]);
    float lg[NE];
    #pragma unroll
    for (int e = 0; e < NE; ++e){
        const float* wr = Wr + (size_t)e * D_MODEL;
        float s = 0.f;
        #pragma unroll
        for (int c = 0; c < 8; ++c) s = fmaf(xv[c], wr[lane + 64*c], s);
        #pragma unroll
        for (int off = 32; off; off >>= 1) s += __shfl_xor(s, off);
        lg[e] = s;
    }
    if (lane == 0){
        float m = lg[0];
        #pragma unroll
        for (int e = 1; e < NE; ++e) m = fmaxf(m, lg[e]);
        float sum = 0.f;
        #pragma unroll
        for (int e = 0; e < NE; ++e) sum += expf(lg[e] - m);
        int i0 = 0; float v0 = lg[0];
        #pragma unroll
        for (int e = 1; e < NE; ++e) if (lg[e] > v0){ v0 = lg[e]; i0 = e; }
        int i1 = -1; float v1 = -1e30f;
        #pragma unroll
        for (int e = 0; e < NE; ++e) if (e != i0 && lg[e] > v1){ v1 = lg[e]; i1 = e; }
        float inv = 1.f / sum;
        pair_prob[2*t]   = expf(v0 - m) * inv;
        pair_prob[2*t+1] = expf(v1 - m) * inv;
        int pos0 = atomicAdd(&cnt[i0], 1);
        lists[i0 * T_TOK + pos0] = 2*t;
        int pos1 = atomicAdd(&cnt[i1], 1);
        lists[i1 * T_TOK + pos1] = 2*t + 1;
    }
}

// ================= GEMM1: H[pair] = GELU(Xg[256] * W1_e^T[256f x 512k]) =================
// 512 thr / 8 waves (2m x 4n), tile 256tok x 256f, BK=64, 2-phase global_load_lds staging.
// LDS: A,B dbuf 4x32KB = 128KB. Swizzle: byte (c2 ^ ((row&7)<<4)) within 128B row.
__global__ __launch_bounds__(512, 2) void gemm1_kernel(const unsigned short* __restrict__ x_bf,
                                                       const unsigned short* __restrict__ W1bf,
                                                       const int* __restrict__ lists,
                                                       const int* __restrict__ cnt,
                                                       unsigned short* __restrict__ H){
    __shared__ __align__(16) unsigned char lds_a[2][32768];
    __shared__ __align__(16) unsigned char lds_b[2][32768];
    __shared__ int s_tok[256];
    __shared__ int s_pair[256];

    int bid = blockIdx.x;
    int f0  = (bid & 7) * 256;
    int rem = bid >> 3, e = -1, tm = 0;
    #pragma unroll
    for (int i = 0; i < NE; ++i){
        int mt = (cnt[i] + 255) >> 8;
        if (e < 0){ if (rem < mt){ e = i; tm = rem; } else rem -= mt; }
    }
    if (e < 0) return;
    int ne = cnt[e];

    int tid = threadIdx.x;
    if (tid < 256){
        int idx = tm * 256 + tid;
        int pair = (idx < ne) ? lists[e * T_TOK + idx] : 0;
        s_pair[tid] = pair;
        s_tok[tid]  = (idx < ne) ? (pair >> 1) : 0;
    }
    __syncthreads();

    int wv = tid >> 6, lane = tid & 63, l15 = lane & 15, lk = lane >> 4;
    int wm = wv >> 2, wn = wv & 3;

    // per-thread staging pointers (4 rows each for A and B)
    const unsigned short* pa[4];
    const unsigned short* pb[4];
    #pragma unroll
    for (int j = 0; j < 4; ++j){
        int row = (wv * 4 + j) * 8 + (lane >> 3);
        int sc  = ((lane & 7) * 8) ^ ((row & 7) * 8);
        pa[j] = x_bf + (size_t)s_tok[row] * D_MODEL + sc;
        pb[j] = W1bf + ((size_t)e * D_FF + f0 + row) * D_MODEL + sc;
    }

    f32x4 zero4 = {0.f, 0.f, 0.f, 0.f};
    f32x4 acc[8][4];
    #pragma unroll
    for (int i = 0; i < 8; ++i)
        #pragma unroll
        for (int j = 0; j < 4; ++j) acc[i][j] = zero4;

    #define G1_STAGE(buf, k) { \
        unsigned char* lab = lds_a[buf] + wv * 4096; \
        unsigned char* lbb = lds_b[buf] + wv * 4096; \
        _Pragma("unroll") \
        for (int j = 0; j < 4; ++j){ \
            gload16(pa[j] + (k) * 64, lab + j * 1024); \
            gload16(pb[j] + (k) * 64, lbb + j * 1024); \
        } }

    G1_STAGE(0, 0);
    __syncthreads();

    for (int k = 0; k < 8; ++k){
        if (k + 1 < 8) G1_STAGE((k + 1) & 1, k + 1);
        const unsigned char* la = lds_a[k & 1];
        const unsigned char* lb = lds_b[k & 1];
        #pragma unroll
        for (int kk = 0; kk < 2; ++kk){
            int c2 = (kk * 32 + lk * 8) * 2;
            bf16x8 bfr[4];
            #pragma unroll
            for (int nf = 0; nf < 4; ++nf){
                int row = wn * 64 + nf * 16 + l15;
                bfr[nf] = *(const bf16x8*)(lb + row * 128 + (c2 ^ ((row & 7) << 4)));
            }
            #pragma unroll
            for (int mf = 0; mf < 8; ++mf){
                int row = wm * 128 + mf * 16 + l15;
                bf16x8 afr = *(const bf16x8*)(la + row * 128 + (c2 ^ ((row & 7) << 4)));
                #pragma unroll
                for (int nf = 0; nf < 4; ++nf)
                    acc[mf][nf] = __builtin_amdgcn_mfma_f32_16x16x32_bf16(afr, bfr[nf], acc[mf][nf], 0, 0, 0);
            }
        }
        __syncthreads();
    }
    #undef G1_STAGE

    // epilogue: GELU -> bf16 -> H[pair][f]
    #pragma unroll
    for (int mf = 0; mf < 8; ++mf){
        #pragma unroll
        for (int r = 0; r < 4; ++r){
            int row = wm * 128 + mf * 16 + lk * 4 + r;
            int idx = tm * 256 + row;
            if (idx < ne){
                int pair = s_pair[row];
                unsigned short* hrow = H + (size_t)pair * D_FF + f0 + wn * 64 + l15;
                #pragma unroll
                for (int nf = 0; nf < 4; ++nf)
                    hrow[nf * 16] = f2bf(gelu_f(acc[mf][nf][r]));
            }
        }
    }
}

// ================= GEMM2: out[tok] += p * (H[128] * W2_e^T[256d x 2048f]) =================
// 512 thr / 8 waves (2m x 4n), tile 128tok x 256d, BK=64, 3-deep ring staging.
// LDS: A 3x16KB + B 3x32KB = 144KB.
__global__ __launch_bounds__(512, 2) void gemm2_kernel(const unsigned short* __restrict__ H,
                                                       const unsigned short* __restrict__ W2bf,
                                                       const float* __restrict__ pair_prob,
                                                       const int* __restrict__ lists,
                                                       const int* __restrict__ cnt,
                                                       float* __restrict__ out){
    __shared__ __align__(16) unsigned char lds_a[3][16384];
    __shared__ __align__(16) unsigned char lds_b[3][32768];
    __shared__ int s_pair[128];

    int bid = blockIdx.x;
    int d0  = (bid & 1) * 256;
    int rem = bid >> 1, e = -1, tm = 0;
    #pragma unroll
    for (int i = 0; i < NE; ++i){
        int mt = (cnt[i] + 127) >> 7;
        if (e < 0){ if (rem < mt){ e = i; tm = rem; } else rem -= mt; }
    }
    if (e < 0) return;
    int ne = cnt[e];

    int tid = threadIdx.x;
    if (tid < 128){
        int idx = tm * 128 + tid;
        s_pair[tid] = (idx < ne) ? lists[e * T_TOK + idx] : 0;
    }
    __syncthreads();

    int wv = tid >> 6, lane = tid & 63, l15 = lane & 15, lk = lane >> 4;
    int wm = wv >> 2, wn = wv & 3;

    const unsigned short* pa[2];
    const unsigned short* pb[4];
    #pragma unroll
    for (int j = 0; j < 2; ++j){
        int row = (wv * 2 + j) * 8 + (lane >> 3);
        int sc  = ((lane & 7) * 8) ^ ((row & 7) * 8);
        pa[j] = H + (size_t)(s_pair[row] >> 1 == (s_pair[row] >> 1) ? s_pair[row] : 0) * D_FF + sc; // s_pair[row] pair id
    }
    #pragma unroll
    for (int j = 0; j < 4; ++j){
        int row = (wv * 4 + j) * 8 + (lane >> 3);
        int sc  = ((lane & 7) * 8) ^ ((row & 7) * 8);
        pb[j] = W2bf + ((size_t)e * D_MODEL + d0 + row) * D_FF + sc;
    }

    f32x4 zero4 = {0.f, 0.f, 0.f, 0.f};
    f32x4 acc[4][4];
    #pragma unroll
    for (int i = 0; i < 4; ++i)
        #pragma unroll
        for (int j = 0; j < 4; ++j) acc[i][j] = zero4;

    #define G2_STAGE(buf, k) { \
        unsigned char* lab = lds_a[buf] + wv * 2048; \
        unsigned char* lbb = lds_b[buf] + wv * 4096; \
        _Pragma("unroll") \
        for (int j = 0; j < 2; ++j) gload16(pa[j] + (k) * 64, lab + j * 1024); \
        _Pragma("unroll") \
        for (int j = 0; j < 4; ++j) gload16(pb[j] + (k) * 64, lbb + j * 1024); \
    }

    G2_STAGE(0, 0);
    G2_STAGE(1, 1);
    __syncthreads();

    int sl = 2, cp = 0;
    for (int k = 0; k < 32; ++k){
        if (k + 2 < 32) G2_STAGE(sl, k + 2);
        const unsigned char* la = lds_a[cp];
        const unsigned char* lb = lds_b[cp];
        #pragma unroll
        for (int kk = 0; kk < 2; ++kk){
            int c2 = (kk * 32 + lk * 8) * 2;
            bf16x8 bfr[4];
            #pragma unroll
            for (int nf = 0; nf < 4; ++nf){
                int row = wn * 64 + nf * 16 + l15;
                bfr[nf] = *(const bf16x8*)(lb + row * 128 + (c2 ^ ((row & 7) << 4)));
            }
            #pragma unroll
            for (int mf = 0; mf < 4; ++mf){
                int row = wm * 64 + mf * 16 + l15;
                bf16x8 afr = *(const bf16x8*)(la + row * 128 + (c2 ^ ((row & 7) << 4)));
                #pragma unroll
                for (int nf = 0; nf < 4; ++nf)
                    acc[mf][nf] = __builtin_amdgcn_mfma_f32_16x16x32_bf16(afr, bfr[nf], acc[mf][nf], 0, 0, 0);
            }
        }
        __syncthreads();
        sl = (sl == 2) ? 0 : sl + 1;
        cp = (cp == 2) ? 0 : cp + 1;
    }
    #undef G2_STAGE

    // epilogue: out[tok] += p * y   (exactly 2 commutative f32 atomics per element)
    #pragma unroll
    for (int mf = 0; mf < 4; ++mf){
        #pragma unroll
        for (int r = 0; r < 4; ++r){
            int row = wm * 64 + mf * 16 + lk * 4 + r;
            int idx = tm * 128 + row;
            if (idx < ne){
                int pair = s_pair[row];
                float p  = pair_prob[pair];
                float* orow = out + (size_t)(pair >> 1) * D_MODEL + d0 + wn * 64 + l15;
                #pragma unroll
                for (int nf = 0; nf < 4; ++nf)
                    atomicAdd(orow + nf * 16, p * acc[mf][nf][r]);
            }
        }
    }
}

// ================= fallback: R4 fused kernel (atomics, used only if ws too small) =================
__global__ __launch_bounds__(512, 2) void moe_ffn_fallback(const unsigned short* __restrict__ x_bf,
                                                           const unsigned short* __restrict__ W1bf,
                                                           const unsigned short* __restrict__ W2bf,
                                                           const float* __restrict__ pair_prob,
                                                           const int* __restrict__ lists,
                                                           const int* __restrict__ cnt,
                                                           float* __restrict__ out){
    __shared__ __align__(16) unsigned char lds_x[64 * 1024];
    __shared__ __align__(16) unsigned char lds_h[64 * 256];
    int bid  = blockIdx.x;
    int xcd  = bid & 7, slot = bid >> 3;
    int eA   = xcd >> 1, sA = xcd & 1;
    int eB   = eA + 4;
    int tA   = (cnt[eA] + 63) >> 6;
    int tB   = (cnt[eB] + 63) >> 6;
    int e, sp, tile;
    if (slot < tA)           { e = eA; sp = sA; tile = slot; }
    else if (slot < tA + tB) { e = eB; sp = sA; tile = slot - tA; }
    else return;
    int ne = cnt[e];
    int tid = threadIdx.x;
    {
        int row = tid >> 3;
        int idx = tile * 64 + row;
        int tok = 0;
        if (idx < ne) tok = lists[e * T_TOK + idx] >> 1;
        int seg = (tid & 7) * 64;
        const unsigned short* src = x_bf + (size_t)tok * D_MODEL + seg;
        int sw = (row & 7) << 4;
        #pragma unroll
        for (int g = 0; g < 8; ++g){
            int4 v = *(const int4*)(src + g * 8);
            int col2 = (seg + g * 8) * 2;
            *(int4*)(lds_x + row * 1024 + (col2 ^ sw)) = v;
        }
    }
    __syncthreads();
    int wv = tid >> 6, lane = tid & 63, l15 = lane & 15, lk = lane >> 4;
    int swz = (l15 & 7) << 4;
    f32x4 zero4 = {0.f, 0.f, 0.f, 0.f};
    f32x4 yacc[4][4];
    #pragma unroll
    for (int i = 0; i < 4; ++i)
        #pragma unroll
        for (int j = 0; j < 4; ++j) yacc[i][j] = zero4;
    const unsigned short* w1p0 = W1bf + ((size_t)e * D_FF + sp * 1024 + wv * 16 + l15) * D_MODEL + lk * 8;
    const unsigned short* w2p0 = W2bf + ((size_t)e * D_MODEL + wv * 64 + l15) * D_FF + sp * 1024 + lk * 8;
    for (int fc = 0; fc < 8; ++fc){
        f32x4 hacc[4];
        #pragma unroll
        for (int at = 0; at < 4; ++at) hacc[at] = zero4;
        const unsigned short* w1p = w1p0 + (size_t)(fc * 128) * D_MODEL;
        #pragma unroll
        for (int ks = 0; ks < 16; ++ks){
            bf16x8 bb = *(const bf16x8*)(w1p + ks * 32);
            int col2 = (ks * 32 + lk * 8) * 2;
            #pragma unroll
            for (int at = 0; at < 4; ++at){
                bf16x8 a = *(const bf16x8*)(lds_x + (at * 16 + l15) * 1024 + (col2 ^ swz));
                hacc[at] = __builtin_amdgcn_mfma_f32_16x16x32_bf16(a, bb, hacc[at], 0, 0, 0);
            }
        }
        {
            int fl2 = (wv * 16 + l15) * 2;
            #pragma unroll
            for (int at = 0; at < 4; ++at){
                #pragma unroll
                for (int r = 0; r < 4; ++r){
                    int tok = at * 16 + lk * 4 + r;
                    *(unsigned short*)(lds_h + tok * 256 + (fl2 ^ ((tok & 7) << 4))) = f2bf(gelu_f(hacc[at][r]));
                }
            }
        }
        asm volatile("s_waitcnt lgkmcnt(0)\n\ts_barrier" ::: "memory");
        const unsigned short* w2p = w2p0 + fc * 128;
        #pragma unroll
        for (int ks2 = 0; ks2 < 4; ++ks2){
            int col2 = (ks2 * 32 + lk * 8) * 2;
            bf16x8 am[4];
            #pragma unroll
            for (int mt = 0; mt < 4; ++mt)
                am[mt] = *(const bf16x8*)(lds_h + (mt * 16 + l15) * 256 + (col2 ^ swz));
            #pragma unroll
            for (int nt = 0; nt < 4; ++nt){
                bf16x8 bb = *(const bf16x8*)(w2p + (size_t)nt * 16 * D_FF + ks2 * 32);
                #pragma unroll
                for (int mt = 0; mt < 4; ++mt)
                    yacc[mt][nt] = __builtin_amdgcn_mfma_f32_16x16x32_bf16(am[mt], bb, yacc[mt][nt], 0, 0, 0);
            }
        }
        asm volatile("s_waitcnt lgkmcnt(0)\n\ts_barrier" ::: "memory");
    }
    const int* lrow = lists + e * T_TOK + tile * 64;
    #pragma unroll
    for (int mt = 0; mt < 4; ++mt){
        #pragma unroll
        for (int r = 0; r < 4; ++r){
            int trow = mt * 16 + lk * 4 + r;
            int idx  = tile * 64 + trow;
            if (idx < ne){
                int pair = lrow[trow];
                float p  = pair_prob[pair];
                float* orow = out + (size_t)(pair >> 1) * D_MODEL;
                #pragma unroll
                for (int nt = 0; nt < 4; ++nt)
                    atomicAdd(orow + wv * 64 + nt * 16 + l15, p * yacc[mt][nt][r]);
            }
        }
    }
}

extern "C" void kernel_launch(void* const* d_in, const int* in_sizes, int n_in,
                              void* d_out, int out_size, void* d_ws, size_t ws_size,
                              hipStream_t stream){
    const float* x  = (const float*)d_in[0];
    const float* Wr = (const float*)d_in[1];
    const float* W1 = (const float*)d_in[2];
    const float* W2 = (const float*)d_in[3];
    float* out = (float*)d_out;

    char* ws = (char*)d_ws;
    unsigned short* x_bf = (unsigned short*)(ws);                  //  8,388,608
    unsigned short* W1bf = (unsigned short*)(ws + 8388608);        // 16,777,216
    unsigned short* W2bf = (unsigned short*)(ws + 25165824);       // 16,777,216
    unsigned short* H    = (unsigned short*)(ws + 41943040);       // 67,108,864
    float* pair_prob     = (float*)(ws + 109051904);               //     65,536
    int*   lists         = (int*)(ws + 109117440);                 //    262,144
    int*   cnt           = (int*)(ws + 109379584);                 //         32
    const size_t NEED = 109379616;
    bool big = ws_size >= NEED;
    if (!big){
        // compact layout (fallback path)
        pair_prob = (float*)(ws + 41943040);
        lists     = (int*)(ws + 42008576);
        cnt       = (int*)(ws + 42270720);
    }

    hipMemsetAsync(cnt, 0, NE * sizeof(int), stream);
    hipMemsetAsync(d_out, 0, (size_t)out_size * sizeof(float), stream);

    cvt_f32_bf16<<<2048, 256, 0, stream>>>(W1, W1bf, (NE * D_FF * D_MODEL) / 4);
    cvt_f32_bf16<<<2048, 256, 0, stream>>>(W2, W2bf, (NE * D_MODEL * D_FF) / 4);

    router_kernel<<<(T_TOK * 64) / 256, 256, 0, stream>>>(x, Wr, x_bf, pair_prob, lists, cnt);

    if (big){
        gemm1_kernel<<<576, 512, 0, stream>>>(x_bf, W1bf, lists, cnt, H);
        gemm2_kernel<<<272, 512, 0, stream>>>(H, W2bf, pair_prob, lists, cnt, out);
    } else {
        moe_ffn_fallback<<<2080, 512, 0, stream>>>(x_bf, W1bf, W2bf, pair_prob, lists, cnt, out);
    }
}

// Round 6
// 230.472 us; speedup vs baseline: 3.5737x; 1.7603x over previous
//
#include <hip/hip_runtime.h>
#include <hip/hip_bf16.h>
#include <math.h>

#define D_MODEL 512
#define D_FF    2048
#define NE      8
#define T_TOK   8192
#define NPAIR   (2 * T_TOK)

typedef __attribute__((ext_vector_type(8))) short bf16x8;
typedef __attribute__((ext_vector_type(4))) float f32x4;

static __device__ __forceinline__ unsigned short f2bf(float f){
    union { float f; unsigned u; } v; v.f = f;
    unsigned r = v.u + 0x7FFFu + ((v.u >> 16) & 1u);   // RNE
    return (unsigned short)(r >> 16);
}

// tanh-form GELU via exp2 (abs err <= ~3e-4, well under bf16 rounding of h)
static __device__ __forceinline__ float gelu_f(float x){
    float z = 0.7978845608028654f * (x + 0.044715f * x * x * x);
    float e = __builtin_amdgcn_exp2f(z * 2.8853900817779268f);  // e^(2z)
    float t = 1.f - 2.f * __builtin_amdgcn_rcpf(e + 1.f);       // tanh(z)
    return 0.5f * x * (1.f + t);
}

static __device__ __forceinline__ void gload16(const void* g, void* l){
    __builtin_amdgcn_global_load_lds((const __attribute__((address_space(1))) unsigned int*)g,
                                     (__attribute__((address_space(3))) unsigned int*)l, 16, 0, 0);
}

// ---------------- f32 -> bf16 conversion (weights) ----------------
__global__ __launch_bounds__(256) void cvt_f32_bf16(const float* __restrict__ src,
                                                    unsigned short* __restrict__ dst,
                                                    int n4){
    int i = blockIdx.x * blockDim.x + threadIdx.x;
    int stride = gridDim.x * blockDim.x;
    for (; i < n4; i += stride){
        float4 v = ((const float4*)src)[i];
        ushort4 o;
        o.x = f2bf(v.x); o.y = f2bf(v.y); o.z = f2bf(v.z); o.w = f2bf(v.w);
        ((ushort4*)dst)[i] = o;
    }
}

// ------------- router v2: block-aggregated (8 atomics per 64 tokens, not 2 per token) -------------
// 512 thr / 8 waves, 64 tokens per block (8 per wave). Wave 0 ranks the block's 128
// expert-entries via unrolled __ballot and reserves list space with ONE atomicAdd/expert.
__global__ __launch_bounds__(512) void router_kernel(const float* __restrict__ x,
                                                     const float* __restrict__ Wr,
                                                     unsigned short* __restrict__ x_bf,
                                                     float* __restrict__ pair_prob,
                                                     int* __restrict__ lists,
                                                     int* __restrict__ cnt){
    __shared__ int s_ei[128];   // expert id per entry (2 per token)

    int tid  = threadIdx.x;
    int wv   = tid >> 6;
    int lane = tid & 63;
    int tblk = blockIdx.x * 64;

    #pragma unroll 1
    for (int i = 0; i < 8; ++i){
        int tl = wv * 8 + i;
        int t  = tblk + tl;
        const float* xr = x + (size_t)t * D_MODEL;
        float xv[8];
        #pragma unroll
        for (int c = 0; c < 8; ++c) xv[c] = xr[lane + 64*c];
        unsigned short* xb = x_bf + (size_t)t * D_MODEL;
        #pragma unroll
        for (int c = 0; c < 8; ++c) xb[lane + 64*c] = f2bf(xv[c]);
        float lg[NE];
        #pragma unroll
        for (int e = 0; e < NE; ++e){
            const float* wr = Wr + (size_t)e * D_MODEL;
            float s = 0.f;
            #pragma unroll
            for (int c = 0; c < 8; ++c) s = fmaf(xv[c], wr[lane + 64*c], s);
            #pragma unroll
            for (int off = 32; off; off >>= 1) s += __shfl_xor(s, off);
            lg[e] = s;
        }
        if (lane == 0){
            float m = lg[0];
            #pragma unroll
            for (int e = 1; e < NE; ++e) m = fmaxf(m, lg[e]);
            float sum = 0.f;
            #pragma unroll
            for (int e = 0; e < NE; ++e) sum += expf(lg[e] - m);
            int i0 = 0; float v0 = lg[0];
            #pragma unroll
            for (int e = 1; e < NE; ++e) if (lg[e] > v0){ v0 = lg[e]; i0 = e; }
            int i1 = -1; float v1 = -1e30f;
            #pragma unroll
            for (int e = 0; e < NE; ++e) if (e != i0 && lg[e] > v1){ v1 = lg[e]; i1 = e; }
            float inv = 1.f / sum;
            pair_prob[2*t]   = expf(v0 - m) * inv;
            pair_prob[2*t+1] = expf(v1 - m) * inv;
            s_ei[2*tl]     = i0;
            s_ei[2*tl + 1] = i1;
        }
    }
    __syncthreads();

    if (wv == 0){
        int e0 = s_ei[lane];        // round-0 entry
        int e1 = s_ei[64 + lane];   // round-1 entry
        unsigned long long below = (lane == 63) ? ~0ull >> 1 : (1ull << lane) - 1;
        unsigned long long m0[NE];
        int rank0 = 0, rank1 = 0, tot = 0;
        #pragma unroll
        for (int ex = 0; ex < NE; ++ex){
            m0[ex] = __ballot(e0 == ex);
            if (e0 == ex) rank0 = __popcll(m0[ex] & below);
        }
        #pragma unroll
        for (int ex = 0; ex < NE; ++ex){
            unsigned long long m1 = __ballot(e1 == ex);
            if (e1 == ex) rank1 = __popcll(m1 & below) + __popcll(m0[ex]);
            if (lane == ex) tot = __popcll(m0[ex]) + __popcll(m1);
        }
        int base_held = 0;
        if (lane < NE) base_held = atomicAdd(&cnt[lane], tot);
        int b0 = __shfl(base_held, e0);
        int b1 = __shfl(base_held, e1);
        int pairbase = blockIdx.x * 128;
        lists[e0 * T_TOK + b0 + rank0] = pairbase + lane;        // entry idx == pair offset
        lists[e1 * T_TOK + b1 + rank1] = pairbase + 64 + lane;
    }
}

// ================= GEMM1: H[pair] = GELU(Xg[256] * W1_e^T[256f x 512k]) =================
// 512 thr / 8 waves (2m x 4n), tile 256tok x 256f, BK=64, 2-phase global_load_lds staging.
// LDS: A,B dbuf 4x32KB = 128KB. Swizzle: byte (c2 ^ ((row&7)<<4)) within 128B row.
__global__ __launch_bounds__(512, 2) void gemm1_kernel(const unsigned short* __restrict__ x_bf,
                                                       const unsigned short* __restrict__ W1bf,
                                                       const int* __restrict__ lists,
                                                       const int* __restrict__ cnt,
                                                       unsigned short* __restrict__ H){
    __shared__ __align__(16) unsigned char lds_a[2][32768];
    __shared__ __align__(16) unsigned char lds_b[2][32768];
    __shared__ int s_tok[256];
    __shared__ int s_pair[256];

    int bid = blockIdx.x;
    int f0  = (bid & 7) * 256;
    int rem = bid >> 3, e = -1, tm = 0;
    #pragma unroll
    for (int i = 0; i < NE; ++i){
        int mt = (cnt[i] + 255) >> 8;
        if (e < 0){ if (rem < mt){ e = i; tm = rem; } else rem -= mt; }
    }
    if (e < 0) return;
    int ne = cnt[e];

    int tid = threadIdx.x;
    if (tid < 256){
        int idx = tm * 256 + tid;
        int pair = (idx < ne) ? lists[e * T_TOK + idx] : 0;
        s_pair[tid] = pair;
        s_tok[tid]  = (idx < ne) ? (pair >> 1) : 0;
    }
    __syncthreads();

    int wv = tid >> 6, lane = tid & 63, l15 = lane & 15, lk = lane >> 4;
    int wm = wv >> 2, wn = wv & 3;

    const unsigned short* pa[4];
    const unsigned short* pb[4];
    #pragma unroll
    for (int j = 0; j < 4; ++j){
        int row = (wv * 4 + j) * 8 + (lane >> 3);
        int sc  = ((lane & 7) * 8) ^ ((row & 7) * 8);
        pa[j] = x_bf + (size_t)s_tok[row] * D_MODEL + sc;
        pb[j] = W1bf + ((size_t)e * D_FF + f0 + row) * D_MODEL + sc;
    }

    f32x4 zero4 = {0.f, 0.f, 0.f, 0.f};
    f32x4 acc[8][4];
    #pragma unroll
    for (int i = 0; i < 8; ++i)
        #pragma unroll
        for (int j = 0; j < 4; ++j) acc[i][j] = zero4;

    #define G1_STAGE(buf, k) { \
        unsigned char* lab = lds_a[buf] + wv * 4096; \
        unsigned char* lbb = lds_b[buf] + wv * 4096; \
        _Pragma("unroll") \
        for (int j = 0; j < 4; ++j){ \
            gload16(pa[j] + (k) * 64, lab + j * 1024); \
            gload16(pb[j] + (k) * 64, lbb + j * 1024); \
        } }

    G1_STAGE(0, 0);
    __syncthreads();

    for (int k = 0; k < 8; ++k){
        if (k + 1 < 8) G1_STAGE((k + 1) & 1, k + 1);
        const unsigned char* la = lds_a[k & 1];
        const unsigned char* lb = lds_b[k & 1];
        #pragma unroll
        for (int kk = 0; kk < 2; ++kk){
            int c2 = (kk * 32 + lk * 8) * 2;
            bf16x8 bfr[4];
            #pragma unroll
            for (int nf = 0; nf < 4; ++nf){
                int row = wn * 64 + nf * 16 + l15;
                bfr[nf] = *(const bf16x8*)(lb + row * 128 + (c2 ^ ((row & 7) << 4)));
            }
            #pragma unroll
            for (int mf = 0; mf < 8; ++mf){
                int row = wm * 128 + mf * 16 + l15;
                bf16x8 afr = *(const bf16x8*)(la + row * 128 + (c2 ^ ((row & 7) << 4)));
                #pragma unroll
                for (int nf = 0; nf < 4; ++nf)
                    acc[mf][nf] = __builtin_amdgcn_mfma_f32_16x16x32_bf16(afr, bfr[nf], acc[mf][nf], 0, 0, 0);
            }
        }
        __syncthreads();
    }
    #undef G1_STAGE

    #pragma unroll
    for (int mf = 0; mf < 8; ++mf){
        #pragma unroll
        for (int r = 0; r < 4; ++r){
            int row = wm * 128 + mf * 16 + lk * 4 + r;
            int idx = tm * 256 + row;
            if (idx < ne){
                int pair = s_pair[row];
                unsigned short* hrow = H + (size_t)pair * D_FF + f0 + wn * 64 + l15;
                #pragma unroll
                for (int nf = 0; nf < 4; ++nf)
                    hrow[nf * 16] = f2bf(gelu_f(acc[mf][nf][r]));
            }
        }
    }
}

// ================= GEMM2: out[tok] += p * (H[128] * W2_e^T[256d x 2048f]) =================
// 512 thr / 8 waves (2m x 4n), tile 128tok x 256d, BK=64, 3-deep ring staging.
__global__ __launch_bounds__(512, 2) void gemm2_kernel(const unsigned short* __restrict__ H,
                                                       const unsigned short* __restrict__ W2bf,
                                                       const float* __restrict__ pair_prob,
                                                       const int* __restrict__ lists,
                                                       const int* __restrict__ cnt,
                                                       float* __restrict__ out){
    __shared__ __align__(16) unsigned char lds_a[3][16384];
    __shared__ __align__(16) unsigned char lds_b[3][32768];
    __shared__ int s_pair[128];

    int bid = blockIdx.x;
    int d0  = (bid & 1) * 256;
    int rem = bid >> 1, e = -1, tm = 0;
    #pragma unroll
    for (int i = 0; i < NE; ++i){
        int mt = (cnt[i] + 127) >> 7;
        if (e < 0){ if (rem < mt){ e = i; tm = rem; } else rem -= mt; }
    }
    if (e < 0) return;
    int ne = cnt[e];

    int tid = threadIdx.x;
    if (tid < 128){
        int idx = tm * 128 + tid;
        s_pair[tid] = (idx < ne) ? lists[e * T_TOK + idx] : 0;
    }
    __syncthreads();

    int wv = tid >> 6, lane = tid & 63, l15 = lane & 15, lk = lane >> 4;
    int wm = wv >> 2, wn = wv & 3;

    const unsigned short* pa[2];
    const unsigned short* pb[4];
    #pragma unroll
    for (int j = 0; j < 2; ++j){
        int row = (wv * 2 + j) * 8 + (lane >> 3);
        int sc  = ((lane & 7) * 8) ^ ((row & 7) * 8);
        pa[j] = H + (size_t)s_pair[row] * D_FF + sc;
    }
    #pragma unroll
    for (int j = 0; j < 4; ++j){
        int row = (wv * 4 + j) * 8 + (lane >> 3);
        int sc  = ((lane & 7) * 8) ^ ((row & 7) * 8);
        pb[j] = W2bf + ((size_t)e * D_MODEL + d0 + row) * D_FF + sc;
    }

    f32x4 zero4 = {0.f, 0.f, 0.f, 0.f};
    f32x4 acc[4][4];
    #pragma unroll
    for (int i = 0; i < 4; ++i)
        #pragma unroll
        for (int j = 0; j < 4; ++j) acc[i][j] = zero4;

    #define G2_STAGE(buf, k) { \
        unsigned char* lab = lds_a[buf] + wv * 2048; \
        unsigned char* lbb = lds_b[buf] + wv * 4096; \
        _Pragma("unroll") \
        for (int j = 0; j < 2; ++j) gload16(pa[j] + (k) * 64, lab + j * 1024); \
        _Pragma("unroll") \
        for (int j = 0; j < 4; ++j) gload16(pb[j] + (k) * 64, lbb + j * 1024); \
    }

    G2_STAGE(0, 0);
    G2_STAGE(1, 1);
    __syncthreads();

    int sl = 2, cp = 0;
    for (int k = 0; k < 32; ++k){
        if (k + 2 < 32) G2_STAGE(sl, k + 2);
        const unsigned char* la = lds_a[cp];
        const unsigned char* lb = lds_b[cp];
        #pragma unroll
        for (int kk = 0; kk < 2; ++kk){
            int c2 = (kk * 32 + lk * 8) * 2;
            bf16x8 bfr[4];
            #pragma unroll
            for (int nf = 0; nf < 4; ++nf){
                int row = wn * 64 + nf * 16 + l15;
                bfr[nf] = *(const bf16x8*)(lb + row * 128 + (c2 ^ ((row & 7) << 4)));
            }
            #pragma unroll
            for (int mf = 0; mf < 4; ++mf){
                int row = wm * 64 + mf * 16 + l15;
                bf16x8 afr = *(const bf16x8*)(la + row * 128 + (c2 ^ ((row & 7) << 4)));
                #pragma unroll
                for (int nf = 0; nf < 4; ++nf)
                    acc[mf][nf] = __builtin_amdgcn_mfma_f32_16x16x32_bf16(afr, bfr[nf], acc[mf][nf], 0, 0, 0);
            }
        }
        __syncthreads();
        sl = (sl == 2) ? 0 : sl + 1;
        cp = (cp == 2) ? 0 : cp + 1;
    }
    #undef G2_STAGE

    #pragma unroll
    for (int mf = 0; mf < 4; ++mf){
        #pragma unroll
        for (int r = 0; r < 4; ++r){
            int row = wm * 64 + mf * 16 + lk * 4 + r;
            int idx = tm * 128 + row;
            if (idx < ne){
                int pair = s_pair[row];
                float p  = pair_prob[pair];
                float* orow = out + (size_t)(pair >> 1) * D_MODEL + d0 + wn * 64 + l15;
                #pragma unroll
                for (int nf = 0; nf < 4; ++nf)
                    atomicAdd(orow + nf * 16, p * acc[mf][nf][r]);
            }
        }
    }
}

// ================= fallback: fused kernel (used only if ws too small) =================
__global__ __launch_bounds__(512, 2) void moe_ffn_fallback(const unsigned short* __restrict__ x_bf,
                                                           const unsigned short* __restrict__ W1bf,
                                                           const unsigned short* __restrict__ W2bf,
                                                           const float* __restrict__ pair_prob,
                                                           const int* __restrict__ lists,
                                                           const int* __restrict__ cnt,
                                                           float* __restrict__ out){
    __shared__ __align__(16) unsigned char lds_x[64 * 1024];
    __shared__ __align__(16) unsigned char lds_h[64 * 256];
    int bid  = blockIdx.x;
    int xcd  = bid & 7, slot = bid >> 3;
    int eA   = xcd >> 1, sA = xcd & 1;
    int eB   = eA + 4;
    int tA   = (cnt[eA] + 63) >> 6;
    int tB   = (cnt[eB] + 63) >> 6;
    int e, sp, tile;
    if (slot < tA)           { e = eA; sp = sA; tile = slot; }
    else if (slot < tA + tB) { e = eB; sp = sA; tile = slot - tA; }
    else return;
    int ne = cnt[e];
    int tid = threadIdx.x;
    {
        int row = tid >> 3;
        int idx = tile * 64 + row;
        int tok = 0;
        if (idx < ne) tok = lists[e * T_TOK + idx] >> 1;
        int seg = (tid & 7) * 64;
        const unsigned short* src = x_bf + (size_t)tok * D_MODEL + seg;
        int sw = (row & 7) << 4;
        #pragma unroll
        for (int g = 0; g < 8; ++g){
            int4 v = *(const int4*)(src + g * 8);
            int col2 = (seg + g * 8) * 2;
            *(int4*)(lds_x + row * 1024 + (col2 ^ sw)) = v;
        }
    }
    __syncthreads();
    int wv = tid >> 6, lane = tid & 63, l15 = lane & 15, lk = lane >> 4;
    int swz = (l15 & 7) << 4;
    f32x4 zero4 = {0.f, 0.f, 0.f, 0.f};
    f32x4 yacc[4][4];
    #pragma unroll
    for (int i = 0; i < 4; ++i)
        #pragma unroll
        for (int j = 0; j < 4; ++j) yacc[i][j] = zero4;
    const unsigned short* w1p0 = W1bf + ((size_t)e * D_FF + sp * 1024 + wv * 16 + l15) * D_MODEL + lk * 8;
    const unsigned short* w2p0 = W2bf + ((size_t)e * D_MODEL + wv * 64 + l15) * D_FF + sp * 1024 + lk * 8;
    for (int fc = 0; fc < 8; ++fc){
        f32x4 hacc[4];
        #pragma unroll
        for (int at = 0; at < 4; ++at) hacc[at] = zero4;
        const unsigned short* w1p = w1p0 + (size_t)(fc * 128) * D_MODEL;
        #pragma unroll
        for (int ks = 0; ks < 16; ++ks){
            bf16x8 bb = *(const bf16x8*)(w1p + ks * 32);
            int col2 = (ks * 32 + lk * 8) * 2;
            #pragma unroll
            for (int at = 0; at < 4; ++at){
                bf16x8 a = *(const bf16x8*)(lds_x + (at * 16 + l15) * 1024 + (col2 ^ swz));
                hacc[at] = __builtin_amdgcn_mfma_f32_16x16x32_bf16(a, bb, hacc[at], 0, 0, 0);
            }
        }
        {
            int fl2 = (wv * 16 + l15) * 2;
            #pragma unroll
            for (int at = 0; at < 4; ++at){
                #pragma unroll
                for (int r = 0; r < 4; ++r){
                    int tok = at * 16 + lk * 4 + r;
                    *(unsigned short*)(lds_h + tok * 256 + (fl2 ^ ((tok & 7) << 4))) = f2bf(gelu_f(hacc[at][r]));
                }
            }
        }
        asm volatile("s_waitcnt lgkmcnt(0)\n\ts_barrier" ::: "memory");
        const unsigned short* w2p = w2p0 + fc * 128;
        #pragma unroll
        for (int ks2 = 0; ks2 < 4; ++ks2){
            int col2 = (ks2 * 32 + lk * 8) * 2;
            bf16x8 am[4];
            #pragma unroll
            for (int mt = 0; mt < 4; ++mt)
                am[mt] = *(const bf16x8*)(lds_h + (mt * 16 + l15) * 256 + (col2 ^ swz));
            #pragma unroll
            for (int nt = 0; nt < 4; ++nt){
                bf16x8 bb = *(const bf16x8*)(w2p + (size_t)nt * 16 * D_FF + ks2 * 32);
                #pragma unroll
                for (int mt = 0; mt < 4; ++mt)
                    yacc[mt][nt] = __builtin_amdgcn_mfma_f32_16x16x32_bf16(am[mt], bb, yacc[mt][nt], 0, 0, 0);
            }
        }
        asm volatile("s_waitcnt lgkmcnt(0)\n\ts_barrier" ::: "memory");
    }
    const int* lrow = lists + e * T_TOK + tile * 64;
    #pragma unroll
    for (int mt = 0; mt < 4; ++mt){
        #pragma unroll
        for (int r = 0; r < 4; ++r){
            int trow = mt * 16 + lk * 4 + r;
            int idx  = tile * 64 + trow;
            if (idx < ne){
                int pair = lrow[trow];
                float p  = pair_prob[pair];
                float* orow = out + (size_t)(pair >> 1) * D_MODEL;
                #pragma unroll
                for (int nt = 0; nt < 4; ++nt)
                    atomicAdd(orow + wv * 64 + nt * 16 + l15, p * yacc[mt][nt][r]);
            }
        }
    }
}

extern "C" void kernel_launch(void* const* d_in, const int* in_sizes, int n_in,
                              void* d_out, int out_size, void* d_ws, size_t ws_size,
                              hipStream_t stream){
    const float* x  = (const float*)d_in[0];
    const float* Wr = (const float*)d_in[1];
    const float* W1 = (const float*)d_in[2];
    const float* W2 = (const float*)d_in[3];
    float* out = (float*)d_out;

    char* ws = (char*)d_ws;
    unsigned short* x_bf = (unsigned short*)(ws);                  //  8,388,608
    unsigned short* W1bf = (unsigned short*)(ws + 8388608);        // 16,777,216
    unsigned short* W2bf = (unsigned short*)(ws + 25165824);       // 16,777,216
    unsigned short* H    = (unsigned short*)(ws + 41943040);       // 67,108,864
    float* pair_prob     = (float*)(ws + 109051904);               //     65,536
    int*   lists         = (int*)(ws + 109117440);                 //    262,144
    int*   cnt           = (int*)(ws + 109379584);                 //         32
    const size_t NEED = 109379616;
    bool big = ws_size >= NEED;
    if (!big){
        pair_prob = (float*)(ws + 41943040);
        lists     = (int*)(ws + 42008576);
        cnt       = (int*)(ws + 42270720);
    }

    hipMemsetAsync(cnt, 0, NE * sizeof(int), stream);
    hipMemsetAsync(d_out, 0, (size_t)out_size * sizeof(float), stream);

    cvt_f32_bf16<<<2048, 256, 0, stream>>>(W1, W1bf, (NE * D_FF * D_MODEL) / 4);
    cvt_f32_bf16<<<2048, 256, 0, stream>>>(W2, W2bf, (NE * D_MODEL * D_FF) / 4);

    router_kernel<<<T_TOK / 64, 512, 0, stream>>>(x, Wr, x_bf, pair_prob, lists, cnt);

    if (big){
        gemm1_kernel<<<576, 512, 0, stream>>>(x_bf, W1bf, lists, cnt, H);
        gemm2_kernel<<<272, 512, 0, stream>>>(H, W2bf, pair_prob, lists, cnt, out);
    } else {
        moe_ffn_fallback<<<2080, 512, 0, stream>>>(x_bf, W1bf, W2bf, pair_prob, lists, cnt, out);
    }
}

// Round 7
// 193.061 us; speedup vs baseline: 4.2662x; 1.1938x over previous
//
#include <hip/hip_runtime.h>
#include <hip/hip_bf16.h>
#include <math.h>

#define D_MODEL 512
#define D_FF    2048
#define NE      8
#define T_TOK   8192

typedef __attribute__((ext_vector_type(8))) short bf16x8;
typedef __attribute__((ext_vector_type(4))) float f32x4;

static __device__ __forceinline__ unsigned short f2bf(float f){
    union { float f; unsigned u; } v; v.f = f;
    unsigned r = v.u + 0x7FFFu + ((v.u >> 16) & 1u);   // RNE
    return (unsigned short)(r >> 16);
}

// tanh-form GELU via exp2 (abs err <= ~3e-4, well under bf16 rounding of h)
static __device__ __forceinline__ float gelu_f(float x){
    float z = 0.7978845608028654f * (x + 0.044715f * x * x * x);
    float e = __builtin_amdgcn_exp2f(z * 2.8853900817779268f);  // e^(2z)
    float t = 1.f - 2.f * __builtin_amdgcn_rcpf(e + 1.f);       // tanh(z)
    return 0.5f * x * (1.f + t);
}

static __device__ __forceinline__ void gload16(const void* g, void* l){
    __builtin_amdgcn_global_load_lds((const __attribute__((address_space(1))) unsigned int*)g,
                                     (__attribute__((address_space(3))) unsigned int*)l, 16, 0, 0);
}

// ---------------- f32 -> bf16 conversion (weights) ----------------
__global__ __launch_bounds__(256) void cvt_f32_bf16(const float* __restrict__ src,
                                                    unsigned short* __restrict__ dst,
                                                    int n4){
    int i = blockIdx.x * blockDim.x + threadIdx.x;
    int stride = gridDim.x * blockDim.x;
    for (; i < n4; i += stride){
        float4 v = ((const float4*)src)[i];
        ushort4 o;
        o.x = f2bf(v.x); o.y = f2bf(v.y); o.z = f2bf(v.z); o.w = f2bf(v.w);
        ((ushort4*)dst)[i] = o;
    }
}

// ------------- router: block-aggregated top-2 (8 atomics per 64 tokens) -------------
__global__ __launch_bounds__(512) void router_kernel(const float* __restrict__ x,
                                                     const float* __restrict__ Wr,
                                                     unsigned short* __restrict__ x_bf,
                                                     float* __restrict__ pair_prob,
                                                     int* __restrict__ lists,
                                                     int* __restrict__ cnt){
    __shared__ int s_ei[128];

    int tid  = threadIdx.x;
    int wv   = tid >> 6;
    int lane = tid & 63;
    int tblk = blockIdx.x * 64;

    #pragma unroll 1
    for (int i = 0; i < 8; ++i){
        int tl = wv * 8 + i;
        int t  = tblk + tl;
        const float* xr = x + (size_t)t * D_MODEL;
        float xv[8];
        #pragma unroll
        for (int c = 0; c < 8; ++c) xv[c] = xr[lane + 64*c];
        unsigned short* xb = x_bf + (size_t)t * D_MODEL;
        #pragma unroll
        for (int c = 0; c < 8; ++c) xb[lane + 64*c] = f2bf(xv[c]);
        float lg[NE];
        #pragma unroll
        for (int e = 0; e < NE; ++e){
            const float* wr = Wr + (size_t)e * D_MODEL;
            float s = 0.f;
            #pragma unroll
            for (int c = 0; c < 8; ++c) s = fmaf(xv[c], wr[lane + 64*c], s);
            #pragma unroll
            for (int off = 32; off; off >>= 1) s += __shfl_xor(s, off);
            lg[e] = s;
        }
        if (lane == 0){
            float m = lg[0];
            #pragma unroll
            for (int e = 1; e < NE; ++e) m = fmaxf(m, lg[e]);
            float sum = 0.f;
            #pragma unroll
            for (int e = 0; e < NE; ++e) sum += expf(lg[e] - m);
            int i0 = 0; float v0 = lg[0];
            #pragma unroll
            for (int e = 1; e < NE; ++e) if (lg[e] > v0){ v0 = lg[e]; i0 = e; }
            int i1 = -1; float v1 = -1e30f;
            #pragma unroll
            for (int e = 0; e < NE; ++e) if (e != i0 && lg[e] > v1){ v1 = lg[e]; i1 = e; }
            float inv = 1.f / sum;
            pair_prob[2*t]   = expf(v0 - m) * inv;
            pair_prob[2*t+1] = expf(v1 - m) * inv;
            s_ei[2*tl]     = i0;
            s_ei[2*tl + 1] = i1;
        }
    }
    __syncthreads();

    if (wv == 0){
        int e0 = s_ei[lane];
        int e1 = s_ei[64 + lane];
        unsigned long long below = (lane == 63) ? ~0ull >> 1 : (1ull << lane) - 1;
        unsigned long long m0[NE];
        int rank0 = 0, rank1 = 0, tot = 0;
        #pragma unroll
        for (int ex = 0; ex < NE; ++ex){
            m0[ex] = __ballot(e0 == ex);
            if (e0 == ex) rank0 = __popcll(m0[ex] & below);
        }
        #pragma unroll
        for (int ex = 0; ex < NE; ++ex){
            unsigned long long m1 = __ballot(e1 == ex);
            if (e1 == ex) rank1 = __popcll(m1 & below) + __popcll(m0[ex]);
            if (lane == ex) tot = __popcll(m0[ex]) + __popcll(m1);
        }
        int base_held = 0;
        if (lane < NE) base_held = atomicAdd(&cnt[lane], tot);
        int b0 = __shfl(base_held, e0);
        int b1 = __shfl(base_held, e1);
        int pairbase = blockIdx.x * 128;
        lists[e0 * T_TOK + b0 + rank0] = pairbase + lane;
        lists[e1 * T_TOK + b1 + rank1] = pairbase + 64 + lane;
    }
}

// ================= GEMM template pieces =================
// 256 thr / 4 waves (2m x 2n), tile 128x128, BK=32, 3-ring LDS (48KB -> 3 blocks/CU),
// counted vmcnt (never drains in main loop), 64B-row LDS with slot^=(row&3) swizzle.

// GEMM1: H[pair, f] = GELU( Xg[128 pairs] * W1_e^T ), K = 512 (16 steps)
__global__ __launch_bounds__(256, 4) void gemm1_kernel(const unsigned short* __restrict__ x_bf,
                                                       const unsigned short* __restrict__ W1bf,
                                                       const int* __restrict__ lists,
                                                       const int* __restrict__ cnt,
                                                       unsigned short* __restrict__ H){
    __shared__ __align__(16) unsigned char lds_a[3][8192];
    __shared__ __align__(16) unsigned char lds_b[3][8192];
    __shared__ int s_tok[128];
    __shared__ int s_pair[128];

    int bid = blockIdx.x;
    int f0  = (bid & 15) << 7;
    int rem = bid >> 4, e = -1, tm = 0;
    for (int i = 0; i < NE; ++i){
        int mt = (cnt[i] + 127) >> 7;
        if (e < 0){ if (rem < mt){ e = i; tm = rem; } else rem -= mt; }
    }
    if (e < 0) return;
    int ne = cnt[e];

    int tid = threadIdx.x;
    if (tid < 128){
        int idx = tm * 128 + tid;
        int pair = (idx < ne) ? lists[e * T_TOK + idx] : 0;
        s_pair[tid] = pair;
        s_tok[tid]  = (idx < ne) ? (pair >> 1) : 0;
    }
    __syncthreads();

    int wv = tid >> 6, lane = tid & 63, l15 = lane & 15, lk = lane >> 4;
    int wm = wv >> 1, wn = wv & 1;

    // staging: lane covers row (r*64 + wv*16 + (lane>>2)), slot (lane&3); src slot = slot ^ (row&3)
    int rl  = lane >> 2;
    int sl8 = ((lane & 3) ^ (rl & 3)) * 8;
    int rowA0 = wv * 16 + rl, rowA1 = 64 + wv * 16 + rl;
    const unsigned short* pa0 = x_bf + (size_t)s_tok[rowA0] * D_MODEL + sl8;
    const unsigned short* pa1 = x_bf + (size_t)s_tok[rowA1] * D_MODEL + sl8;
    const unsigned short* pb0 = W1bf + ((size_t)e * D_FF + f0 + rowA0) * D_MODEL + sl8;
    const unsigned short* pb1 = W1bf + ((size_t)e * D_FF + f0 + rowA1) * D_MODEL + sl8;
    int dstoff = wv * 16 * 64;   // wave-uniform dest base offset (lane*16 added by HW)

    f32x4 zero4 = {0.f, 0.f, 0.f, 0.f};
    f32x4 acc[4][4];
    #pragma unroll
    for (int i = 0; i < 4; ++i)
        #pragma unroll
        for (int j = 0; j < 4; ++j) acc[i][j] = zero4;

    int ro = ((lk ^ (l15 & 3)) << 4);   // reader slot xor (row&3 == l15&3 for 16-aligned row bases)

    #define G1_STAGE(s, k) { \
        unsigned char* da = lds_a[s] + dstoff; \
        unsigned char* db = lds_b[s] + dstoff; \
        gload16(pa0 + (k) * 32, da); \
        gload16(pa1 + (k) * 32, da + 4096); \
        gload16(pb0 + (k) * 32, db); \
        gload16(pb1 + (k) * 32, db + 4096); }

    G1_STAGE(0, 0);
    G1_STAGE(1, 1);
    int sl = 2, cp = 0;

    #pragma unroll 1
    for (int k = 0; k < 16; ++k){
        if (k < 14){
            G1_STAGE(sl, k + 2);
            asm volatile("s_waitcnt vmcnt(8)\n\ts_barrier" ::: "memory");
        } else if (k == 14){
            asm volatile("s_waitcnt vmcnt(4)\n\ts_barrier" ::: "memory");
        } else {
            asm volatile("s_waitcnt vmcnt(0)\n\ts_barrier" ::: "memory");
        }
        const unsigned char* la = lds_a[cp];
        const unsigned char* lb = lds_b[cp];
        bf16x8 a[4], b[4];
        #pragma unroll
        for (int mf = 0; mf < 4; ++mf)
            a[mf] = *(const bf16x8*)(la + (wm * 64 + mf * 16 + l15) * 64 + ro);
        #pragma unroll
        for (int nf = 0; nf < 4; ++nf)
            b[nf] = *(const bf16x8*)(lb + (wn * 64 + nf * 16 + l15) * 64 + ro);
        #pragma unroll
        for (int mf = 0; mf < 4; ++mf)
            #pragma unroll
            for (int nf = 0; nf < 4; ++nf)
                acc[mf][nf] = __builtin_amdgcn_mfma_f32_16x16x32_bf16(a[mf], b[nf], acc[mf][nf], 0, 0, 0);
        asm volatile("s_waitcnt lgkmcnt(0)\n\ts_barrier" ::: "memory");
        sl = (sl == 2) ? 0 : sl + 1;
        cp = (cp == 2) ? 0 : cp + 1;
    }
    #undef G1_STAGE

    // epilogue: GELU -> bf16 -> H[pair][f]
    #pragma unroll
    for (int mf = 0; mf < 4; ++mf){
        #pragma unroll
        for (int r = 0; r < 4; ++r){
            int trow = wm * 64 + mf * 16 + lk * 4 + r;
            int idx  = tm * 128 + trow;
            if (idx < ne){
                unsigned short* hrow = H + (size_t)s_pair[trow] * D_FF + f0 + wn * 64 + l15;
                #pragma unroll
                for (int nf = 0; nf < 4; ++nf)
                    hrow[nf * 16] = f2bf(gelu_f(acc[mf][nf][r]));
            }
        }
    }
}

// GEMM2: out[tok] += p * (H[128 pairs] * W2_e^T[128d]), K = 2048 (64 steps)
__global__ __launch_bounds__(256, 4) void gemm2_kernel(const unsigned short* __restrict__ H,
                                                       const unsigned short* __restrict__ W2bf,
                                                       const float* __restrict__ pair_prob,
                                                       const int* __restrict__ lists,
                                                       const int* __restrict__ cnt,
                                                       float* __restrict__ out){
    __shared__ __align__(16) unsigned char lds_a[3][8192];
    __shared__ __align__(16) unsigned char lds_b[3][8192];
    __shared__ int s_pair[128];

    int bid = blockIdx.x;
    int d0  = (bid & 3) << 7;
    int rem = bid >> 2, e = -1, tm = 0;
    for (int i = 0; i < NE; ++i){
        int mt = (cnt[i] + 127) >> 7;
        if (e < 0){ if (rem < mt){ e = i; tm = rem; } else rem -= mt; }
    }
    if (e < 0) return;
    int ne = cnt[e];

    int tid = threadIdx.x;
    if (tid < 128){
        int idx = tm * 128 + tid;
        s_pair[tid] = (idx < ne) ? lists[e * T_TOK + idx] : 0;
    }
    __syncthreads();

    int wv = tid >> 6, lane = tid & 63, l15 = lane & 15, lk = lane >> 4;
    int wm = wv >> 1, wn = wv & 1;

    int rl  = lane >> 2;
    int sl8 = ((lane & 3) ^ (rl & 3)) * 8;
    int rowA0 = wv * 16 + rl, rowA1 = 64 + wv * 16 + rl;
    const unsigned short* pa0 = H + (size_t)s_pair[rowA0] * D_FF + sl8;
    const unsigned short* pa1 = H + (size_t)s_pair[rowA1] * D_FF + sl8;
    const unsigned short* pb0 = W2bf + ((size_t)e * D_MODEL + d0 + rowA0) * D_FF + sl8;
    const unsigned short* pb1 = W2bf + ((size_t)e * D_MODEL + d0 + rowA1) * D_FF + sl8;
    int dstoff = wv * 16 * 64;

    f32x4 zero4 = {0.f, 0.f, 0.f, 0.f};
    f32x4 acc[4][4];
    #pragma unroll
    for (int i = 0; i < 4; ++i)
        #pragma unroll
        for (int j = 0; j < 4; ++j) acc[i][j] = zero4;

    int ro = ((lk ^ (l15 & 3)) << 4);

    #define G2_STAGE(s, k) { \
        unsigned char* da = lds_a[s] + dstoff; \
        unsigned char* db = lds_b[s] + dstoff; \
        gload16(pa0 + (k) * 32, da); \
        gload16(pa1 + (k) * 32, da + 4096); \
        gload16(pb0 + (k) * 32, db); \
        gload16(pb1 + (k) * 32, db + 4096); }

    G2_STAGE(0, 0);
    G2_STAGE(1, 1);
    int sl = 2, cp = 0;

    #pragma unroll 1
    for (int k = 0; k < 64; ++k){
        if (k < 62){
            G2_STAGE(sl, k + 2);
            asm volatile("s_waitcnt vmcnt(8)\n\ts_barrier" ::: "memory");
        } else if (k == 62){
            asm volatile("s_waitcnt vmcnt(4)\n\ts_barrier" ::: "memory");
        } else {
            asm volatile("s_waitcnt vmcnt(0)\n\ts_barrier" ::: "memory");
        }
        const unsigned char* la = lds_a[cp];
        const unsigned char* lb = lds_b[cp];
        bf16x8 a[4], b[4];
        #pragma unroll
        for (int mf = 0; mf < 4; ++mf)
            a[mf] = *(const bf16x8*)(la + (wm * 64 + mf * 16 + l15) * 64 + ro);
        #pragma unroll
        for (int nf = 0; nf < 4; ++nf)
            b[nf] = *(const bf16x8*)(lb + (wn * 64 + nf * 16 + l15) * 64 + ro);
        #pragma unroll
        for (int mf = 0; mf < 4; ++mf)
            #pragma unroll
            for (int nf = 0; nf < 4; ++nf)
                acc[mf][nf] = __builtin_amdgcn_mfma_f32_16x16x32_bf16(a[mf], b[nf], acc[mf][nf], 0, 0, 0);
        asm volatile("s_waitcnt lgkmcnt(0)\n\ts_barrier" ::: "memory");
        sl = (sl == 2) ? 0 : sl + 1;
        cp = (cp == 2) ? 0 : cp + 1;
    }
    #undef G2_STAGE

    // epilogue: out[tok] += p * y   (exactly 2 commutative f32 atomics per element)
    #pragma unroll
    for (int mf = 0; mf < 4; ++mf){
        #pragma unroll
        for (int r = 0; r < 4; ++r){
            int trow = wm * 64 + mf * 16 + lk * 4 + r;
            int idx  = tm * 128 + trow;
            if (idx < ne){
                int pair = s_pair[trow];
                float p  = pair_prob[pair];
                float* orow = out + (size_t)(pair >> 1) * D_MODEL + d0 + wn * 64 + l15;
                #pragma unroll
                for (int nf = 0; nf < 4; ++nf)
                    atomicAdd(orow + nf * 16, p * acc[mf][nf][r]);
            }
        }
    }
}

// ================= fallback: fused kernel (used only if ws too small) =================
__global__ __launch_bounds__(512, 2) void moe_ffn_fallback(const unsigned short* __restrict__ x_bf,
                                                           const unsigned short* __restrict__ W1bf,
                                                           const unsigned short* __restrict__ W2bf,
                                                           const float* __restrict__ pair_prob,
                                                           const int* __restrict__ lists,
                                                           const int* __restrict__ cnt,
                                                           float* __restrict__ out){
    __shared__ __align__(16) unsigned char lds_x[64 * 1024];
    __shared__ __align__(16) unsigned char lds_h[64 * 256];
    int bid  = blockIdx.x;
    int xcd  = bid & 7, slot = bid >> 3;
    int eA   = xcd >> 1, sA = xcd & 1;
    int eB   = eA + 4;
    int tA   = (cnt[eA] + 63) >> 6;
    int tB   = (cnt[eB] + 63) >> 6;
    int e, sp, tile;
    if (slot < tA)           { e = eA; sp = sA; tile = slot; }
    else if (slot < tA + tB) { e = eB; sp = sA; tile = slot - tA; }
    else return;
    int ne = cnt[e];
    int tid = threadIdx.x;
    {
        int row = tid >> 3;
        int idx = tile * 64 + row;
        int tok = 0;
        if (idx < ne) tok = lists[e * T_TOK + idx] >> 1;
        int seg = (tid & 7) * 64;
        const unsigned short* src = x_bf + (size_t)tok * D_MODEL + seg;
        int sw = (row & 7) << 4;
        #pragma unroll
        for (int g = 0; g < 8; ++g){
            int4 v = *(const int4*)(src + g * 8);
            int col2 = (seg + g * 8) * 2;
            *(int4*)(lds_x + row * 1024 + (col2 ^ sw)) = v;
        }
    }
    __syncthreads();
    int wv = tid >> 6, lane = tid & 63, l15 = lane & 15, lk = lane >> 4;
    int swz = (l15 & 7) << 4;
    f32x4 zero4 = {0.f, 0.f, 0.f, 0.f};
    f32x4 yacc[4][4];
    #pragma unroll
    for (int i = 0; i < 4; ++i)
        #pragma unroll
        for (int j = 0; j < 4; ++j) yacc[i][j] = zero4;
    const unsigned short* w1p0 = W1bf + ((size_t)e * D_FF + sp * 1024 + wv * 16 + l15) * D_MODEL + lk * 8;
    const unsigned short* w2p0 = W2bf + ((size_t)e * D_MODEL + wv * 64 + l15) * D_FF + sp * 1024 + lk * 8;
    for (int fc = 0; fc < 8; ++fc){
        f32x4 hacc[4];
        #pragma unroll
        for (int at = 0; at < 4; ++at) hacc[at] = zero4;
        const unsigned short* w1p = w1p0 + (size_t)(fc * 128) * D_MODEL;
        #pragma unroll
        for (int ks = 0; ks < 16; ++ks){
            bf16x8 bb = *(const bf16x8*)(w1p + ks * 32);
            int col2 = (ks * 32 + lk * 8) * 2;
            #pragma unroll
            for (int at = 0; at < 4; ++at){
                bf16x8 a = *(const bf16x8*)(lds_x + (at * 16 + l15) * 1024 + (col2 ^ swz));
                hacc[at] = __builtin_amdgcn_mfma_f32_16x16x32_bf16(a, bb, hacc[at], 0, 0, 0);
            }
        }
        {
            int fl2 = (wv * 16 + l15) * 2;
            #pragma unroll
            for (int at = 0; at < 4; ++at){
                #pragma unroll
                for (int r = 0; r < 4; ++r){
                    int tok = at * 16 + lk * 4 + r;
                    *(unsigned short*)(lds_h + tok * 256 + (fl2 ^ ((tok & 7) << 4))) = f2bf(gelu_f(hacc[at][r]));
                }
            }
        }
        asm volatile("s_waitcnt lgkmcnt(0)\n\ts_barrier" ::: "memory");
        const unsigned short* w2p = w2p0 + fc * 128;
        #pragma unroll
        for (int ks2 = 0; ks2 < 4; ++ks2){
            int col2 = (ks2 * 32 + lk * 8) * 2;
            bf16x8 am[4];
            #pragma unroll
            for (int mt = 0; mt < 4; ++mt)
                am[mt] = *(const bf16x8*)(lds_h + (mt * 16 + l15) * 256 + (col2 ^ swz));
            #pragma unroll
            for (int nt = 0; nt < 4; ++nt){
                bf16x8 bb = *(const bf16x8*)(w2p + (size_t)nt * 16 * D_FF + ks2 * 32);
                #pragma unroll
                for (int mt = 0; mt < 4; ++mt)
                    yacc[mt][nt] = __builtin_amdgcn_mfma_f32_16x16x32_bf16(am[mt], bb, yacc[mt][nt], 0, 0, 0);
            }
        }
        asm volatile("s_waitcnt lgkmcnt(0)\n\ts_barrier" ::: "memory");
    }
    const int* lrow = lists + e * T_TOK + tile * 64;
    #pragma unroll
    for (int mt = 0; mt < 4; ++mt){
        #pragma unroll
        for (int r = 0; r < 4; ++r){
            int trow = mt * 16 + lk * 4 + r;
            int idx  = tile * 64 + trow;
            if (idx < ne){
                int pair = lrow[trow];
                float p  = pair_prob[pair];
                float* orow = out + (size_t)(pair >> 1) * D_MODEL;
                #pragma unroll
                for (int nt = 0; nt < 4; ++nt)
                    atomicAdd(orow + wv * 64 + nt * 16 + l15, p * yacc[mt][nt][r]);
            }
        }
    }
}

extern "C" void kernel_launch(void* const* d_in, const int* in_sizes, int n_in,
                              void* d_out, int out_size, void* d_ws, size_t ws_size,
                              hipStream_t stream){
    const float* x  = (const float*)d_in[0];
    const float* Wr = (const float*)d_in[1];
    const float* W1 = (const float*)d_in[2];
    const float* W2 = (const float*)d_in[3];
    float* out = (float*)d_out;

    char* ws = (char*)d_ws;
    unsigned short* x_bf = (unsigned short*)(ws);                  //  8,388,608
    unsigned short* W1bf = (unsigned short*)(ws + 8388608);        // 16,777,216
    unsigned short* W2bf = (unsigned short*)(ws + 25165824);       // 16,777,216
    unsigned short* H    = (unsigned short*)(ws + 41943040);       // 67,108,864
    float* pair_prob     = (float*)(ws + 109051904);               //     65,536
    int*   lists         = (int*)(ws + 109117440);                 //    262,144
    int*   cnt           = (int*)(ws + 109379584);                 //         32
    const size_t NEED = 109379616;
    bool big = ws_size >= NEED;
    if (!big){
        pair_prob = (float*)(ws + 41943040);
        lists     = (int*)(ws + 42008576);
        cnt       = (int*)(ws + 42270720);
    }

    hipMemsetAsync(cnt, 0, NE * sizeof(int), stream);
    hipMemsetAsync(d_out, 0, (size_t)out_size * sizeof(float), stream);

    cvt_f32_bf16<<<2048, 256, 0, stream>>>(W1, W1bf, (NE * D_FF * D_MODEL) / 4);
    cvt_f32_bf16<<<2048, 256, 0, stream>>>(W2, W2bf, (NE * D_MODEL * D_FF) / 4);

    router_kernel<<<T_TOK / 64, 512, 0, stream>>>(x, Wr, x_bf, pair_prob, lists, cnt);

    if (big){
        // grids cover worst-case per-expert tile counts (sum ceil <= 136); extra blocks exit early
        gemm1_kernel<<<136 * 16, 256, 0, stream>>>(x_bf, W1bf, lists, cnt, H);
        gemm2_kernel<<<136 * 4, 256, 0, stream>>>(H, W2bf, pair_prob, lists, cnt, out);
    } else {
        moe_ffn_fallback<<<2080, 512, 0, stream>>>(x_bf, W1bf, W2bf, pair_prob, lists, cnt, out);
    }
}